// Round 1
// baseline (2410.299 us; speedup 1.0000x reference)
//
#include <hip/hip_runtime.h>
#include <hip/hip_bf16.h>
#include <cstdint>
#include <cstddef>

// Problem sizes (fixed)
constexpr int SEQ = 8192;
constexpr int DIM = 1024;

typedef __attribute__((ext_vector_type(8))) short short8;   // bf16x8 MFMA frag
typedef __attribute__((ext_vector_type(4))) float f32x4;    // fp32x4 acc frag
typedef __attribute__((ext_vector_type(4))) unsigned short us4;

#define MFMA_BF16 __builtin_amdgcn_mfma_f32_16x16x32_bf16

static __device__ __forceinline__ unsigned short f2bf(float f) {
    uint32_t u = __builtin_bit_cast(uint32_t, f);
    u += 0x7FFFu + ((u >> 16) & 1u);      // round-to-nearest-even
    return (unsigned short)(u >> 16);
}

// ---------------------------------------------------------------------------
// GEMM: C[M,N] = cast_bf16(A[M,K]) @ cast_bf16(B[K,N])
// AMODE: 0 = A fp32, 1 = A bf16.  CMODE: 0 = C bf16 [M,N], 1 = C bf16 [N,M]
// (transposed), 2 = C fp32 [M,N].
// 256 threads = 4 waves (2x2), tile 128x128, BK=32, wave tile 64x64.
// ---------------------------------------------------------------------------
template<int AMODE, int CMODE>
__global__ __launch_bounds__(256, 2)
void gemm_kernel(const void* __restrict__ Ap, const float* __restrict__ B,
                 void* __restrict__ Cp, int M, int N, int K)
{
    __shared__ unsigned short As[128][32];   // [m][k]
    __shared__ unsigned short Bs[128][32];   // [n][k]  (transposed stage)

    const int t    = threadIdx.x;
    const int lane = t & 63, w = t >> 6;
    const int wr   = w >> 1, wc = w & 1;
    const int ln15 = lane & 15, hi = lane >> 4;
    const int brow = blockIdx.y * 128, bcol = blockIdx.x * 128;

    f32x4 acc[4][4] = {};

    for (int k0 = 0; k0 < K; k0 += 32) {
        // ---- stage A tile (128 x 32) as bf16
        if (AMODE == 0) {
            const float* A = (const float*)Ap;
            #pragma unroll
            for (int i = 0; i < 4; ++i) {
                int f = t + 256 * i;               // 0..1023 float4-chunks
                int r = f >> 3, c4 = (f & 7) * 4;
                f32x4 v = *(const f32x4*)(A + (size_t)(brow + r) * K + k0 + c4);
                us4 pk = { f2bf(v[0]), f2bf(v[1]), f2bf(v[2]), f2bf(v[3]) };
                *(us4*)&As[r][c4] = pk;
            }
        } else {
            const unsigned short* A = (const unsigned short*)Ap;
            #pragma unroll
            for (int i = 0; i < 2; ++i) {
                int g = t + 256 * i;               // 0..511 16B-chunks
                int r = g >> 2, q8 = (g & 3) * 8;
                *(short8*)&As[r][q8] =
                    *(const short8*)(A + (size_t)(brow + r) * K + k0 + q8);
            }
        }
        // ---- stage B tile (32 x 128) transposed -> Bs[n][k]
        #pragma unroll
        for (int i = 0; i < 4; ++i) {
            int f = t + 256 * i;                   // 0..1023
            int kr = f >> 5, c4 = (f & 31) * 4;
            f32x4 v = *(const f32x4*)(B + (size_t)(k0 + kr) * N + bcol + c4);
            Bs[c4 + 0][kr] = f2bf(v[0]);
            Bs[c4 + 1][kr] = f2bf(v[1]);
            Bs[c4 + 2][kr] = f2bf(v[2]);
            Bs[c4 + 3][kr] = f2bf(v[3]);
        }
        __syncthreads();

        short8 a[4], b[4];
        #pragma unroll
        for (int m = 0; m < 4; ++m)
            a[m] = *(const short8*)&As[wr * 64 + m * 16 + ln15][hi * 8];
        #pragma unroll
        for (int n = 0; n < 4; ++n)
            b[n] = *(const short8*)&Bs[wc * 64 + n * 16 + ln15][hi * 8];
        #pragma unroll
        for (int m = 0; m < 4; ++m)
            #pragma unroll
            for (int n = 0; n < 4; ++n)
                acc[m][n] = MFMA_BF16(a[m], b[n], acc[m][n], 0, 0, 0);
        __syncthreads();
    }

    // ---- epilogue: C/D layout col = lane&15, row = (lane>>4)*4 + j
    #pragma unroll
    for (int m = 0; m < 4; ++m)
        #pragma unroll
        for (int n = 0; n < 4; ++n)
            #pragma unroll
            for (int j = 0; j < 4; ++j) {
                int row = brow + wr * 64 + m * 16 + hi * 4 + j;
                int col = bcol + wc * 64 + n * 16 + ln15;
                float v = acc[m][n][j];
                if (CMODE == 0)
                    ((unsigned short*)Cp)[(size_t)row * N + col] = f2bf(v);
                else if (CMODE == 1)
                    ((unsigned short*)Cp)[(size_t)col * M + row] = f2bf(v);
                else
                    ((float*)Cp)[(size_t)row * N + col] = v;
            }
}

// ---------------------------------------------------------------------------
// Flash attention, causal, head dim 1024.
// 512 threads = 8 waves. BM = 32 query rows per block, BN = 128 keys/iter.
// Q held in registers as A-fragments. Wave w: QK^T keys [w*16, w*16+16);
// PV d-chunk [w*128, w*128+128). K read from kbuf [S,D], V from vtbuf [D,S].
// Output: silu(O/l) as bf16 written back over this block's Q rows.
// ---------------------------------------------------------------------------
__global__ __launch_bounds__(512, 2)
void attn_kernel(const unsigned short* __restrict__ Qb,
                 const unsigned short* __restrict__ Kb,
                 const unsigned short* __restrict__ VTb,
                 unsigned short* __restrict__ Hb)
{
    __shared__ float Ls[32][128];
    __shared__ unsigned short Ps[32][128];
    __shared__ float mrow[32], lrow[32], arow[32];

    const int t    = threadIdx.x;
    const int lane = t & 63, w = t >> 6;     // wave 0..7
    const int ln15 = lane & 15, hi = lane >> 4;
    const int row0 = blockIdx.x * 32;

    if (t < 32) { mrow[t] = -1e30f; lrow[t] = 0.f; }

    // Q fragments: q[m][dk] = Q[row0 + m*16 + ln15][dk*32 + hi*8 .. +7]
    short8 q[2][32];
    #pragma unroll
    for (int m = 0; m < 2; ++m) {
        const unsigned short* base = Qb + (size_t)(row0 + m * 16 + ln15) * DIM + hi * 8;
        #pragma unroll
        for (int dk = 0; dk < 32; ++dk)
            q[m][dk] = *(const short8*)(base + dk * 32);
    }
    __syncthreads();

    const int nkb = row0 / 128 + 1;
    const float scale = 0.03125f;            // 1/sqrt(1024)

    f32x4 o[2][8] = {};

    for (int kb = 0; kb < nkb; ++kb) {
        const int k0 = kb * 128;

        // ---- QK^T: this wave's 16 keys, full D
        f32x4 s0 = {}, s1 = {};
        {
            const unsigned short* kbase =
                Kb + (size_t)(k0 + w * 16 + ln15) * DIM + hi * 8;
            #pragma unroll
            for (int dk = 0; dk < 32; ++dk) {
                short8 bfr = *(const short8*)(kbase + dk * 32);
                s0 = MFMA_BF16(q[0][dk], bfr, s0, 0, 0, 0);
                s1 = MFMA_BF16(q[1][dk], bfr, s1, 0, 0, 0);
            }
        }
        #pragma unroll
        for (int j = 0; j < 4; ++j) {
            Ls[hi * 4 + j][w * 16 + ln15]      = s0[j] * scale;
            Ls[16 + hi * 4 + j][w * 16 + ln15] = s1[j] * scale;
        }
        __syncthreads();

        // ---- stats: 16 threads per row, 8 elems each
        {
            const int r = t >> 4, seg = t & 15;
            const int gr = row0 + r;
            float mloc = -1e30f;
            #pragma unroll
            for (int e = 0; e < 8; ++e) {
                int c = seg * 8 + e;
                float v = Ls[r][c];
                if (k0 + c > gr) v = -1e30f;
                mloc = fmaxf(mloc, v);
            }
            #pragma unroll
            for (int off = 1; off < 16; off <<= 1)
                mloc = fmaxf(mloc, __shfl_xor(mloc, off, 64));
            if (seg == 0) {
                float mo = mrow[r];
                float mn = fmaxf(mo, mloc);
                mrow[r] = mn;
                arow[r] = __expf(mo - mn);
            }
        }
        __syncthreads();

        // ---- P = exp(L - m), row sums
        {
            const int r = t >> 4, seg = t & 15;
            const int gr = row0 + r;
            float mn = mrow[r];
            float sloc = 0.f;
            #pragma unroll
            for (int e = 0; e < 8; ++e) {
                int c = seg * 8 + e;
                float p = 0.f;
                if (k0 + c <= gr) p = __expf(Ls[r][c] - mn);
                sloc += p;
                Ps[r][c] = f2bf(p);
            }
            #pragma unroll
            for (int off = 1; off < 16; off <<= 1)
                sloc += __shfl_xor(sloc, off, 64);
            if (seg == 0) lrow[r] = lrow[r] * arow[r] + sloc;
        }
        __syncthreads();

        // ---- rescale O, then PV for this wave's 128 d-columns
        {
            float al[2][4];
            #pragma unroll
            for (int m = 0; m < 2; ++m)
                #pragma unroll
                for (int j = 0; j < 4; ++j)
                    al[m][j] = arow[m * 16 + hi * 4 + j];
            #pragma unroll
            for (int m = 0; m < 2; ++m)
                #pragma unroll
                for (int n = 0; n < 8; ++n)
                    #pragma unroll
                    for (int j = 0; j < 4; ++j)
                        o[m][n][j] *= al[m][j];

            #pragma unroll
            for (int kk = 0; kk < 4; ++kk) {
                short8 a0 = *(const short8*)&Ps[ln15][kk * 32 + hi * 8];
                short8 a1 = *(const short8*)&Ps[16 + ln15][kk * 32 + hi * 8];
                const unsigned short* vb =
                    VTb + (size_t)(w * 128 + ln15) * SEQ + k0 + kk * 32 + hi * 8;
                #pragma unroll
                for (int n = 0; n < 8; ++n) {
                    short8 bfr = *(const short8*)(vb + (size_t)(n * 16) * SEQ);
                    o[0][n] = MFMA_BF16(a0, bfr, o[0][n], 0, 0, 0);
                    o[1][n] = MFMA_BF16(a1, bfr, o[1][n], 0, 0, 0);
                }
            }
        }
        __syncthreads();
    }

    // ---- epilogue: h = O/l, silu, bf16, store over this block's Q rows
    #pragma unroll
    for (int m = 0; m < 2; ++m)
        #pragma unroll
        for (int j = 0; j < 4; ++j) {
            int r = m * 16 + hi * 4 + j;
            float linv = 1.0f / lrow[r];
            #pragma unroll
            for (int n = 0; n < 8; ++n) {
                float h = o[m][n][j] * linv;
                float sg = 1.0f / (1.0f + __expf(-h));
                Hb[(size_t)(row0 + r) * DIM + w * 128 + n * 16 + ln15] =
                    f2bf(h * sg);
            }
        }
}

// ---------------------------------------------------------------------------
extern "C" void kernel_launch(void* const* d_in, const int* in_sizes, int n_in,
                              void* d_out, int out_size, void* d_ws, size_t ws_size,
                              hipStream_t stream)
{
    const float* x   = (const float*)d_in[0];
    const float* wq  = (const float*)d_in[1];
    const float* wk  = (const float*)d_in[2];
    const float* wv1 = (const float*)d_in[3];
    const float* wv2 = (const float*)d_in[4];

    const size_t BUF = (size_t)SEQ * DIM * sizeof(unsigned short);  // 16 MiB
    unsigned short* qbuf  = (unsigned short*)d_ws;                  // [S,D] bf16 (later: silu(hidden))
    unsigned short* kbuf  = (unsigned short*)((char*)d_ws + BUF);   // [S,D] bf16
    unsigned short* vtbuf = (unsigned short*)((char*)d_ws + 2*BUF); // [D,S] bf16 (V transposed)

    dim3 gblk(DIM / 128, SEQ / 128);  // (8, 64)

    gemm_kernel<0, 0><<<gblk, 256, 0, stream>>>(x, wq,  qbuf,  SEQ, DIM, DIM);
    gemm_kernel<0, 0><<<gblk, 256, 0, stream>>>(x, wk,  kbuf,  SEQ, DIM, DIM);
    gemm_kernel<0, 1><<<gblk, 256, 0, stream>>>(x, wv1, vtbuf, SEQ, DIM, DIM);

    attn_kernel<<<SEQ / 32, 512, 0, stream>>>(qbuf, kbuf, vtbuf, qbuf);

    gemm_kernel<1, 2><<<gblk, 256, 0, stream>>>(qbuf, wv2, d_out, SEQ, DIM, DIM);
}

// Round 5
// 523.777 us; speedup vs baseline: 4.6018x; 4.6018x over previous
//
#include <hip/hip_runtime.h>
#include <hip/hip_bf16.h>
#include <cstdint>
#include <cstddef>

constexpr int SEQ = 8192;
constexpr int DIM = 1024;

typedef __attribute__((ext_vector_type(8))) short short8;   // bf16x8 MFMA frag
typedef __attribute__((ext_vector_type(4))) float f32x4;    // fp32x4 acc frag
typedef __attribute__((ext_vector_type(4))) unsigned short us4;

#define MFMA_BF16 __builtin_amdgcn_mfma_f32_16x16x32_bf16

static __device__ __forceinline__ unsigned short f2bf(float f) {
    uint32_t u = __builtin_bit_cast(uint32_t, f);
    u += 0x7FFFu + ((u >> 16) & 1u);      // round-to-nearest-even
    return (unsigned short)(u >> 16);
}
static __device__ __forceinline__ float bf2f(unsigned short h) {
    uint32_t u = ((uint32_t)h) << 16;
    return __builtin_bit_cast(float, u);
}

#define GLOAD16(gp, lp) __builtin_amdgcn_global_load_lds(                      \
    (const __attribute__((address_space(1))) void*)(gp),                       \
    (__attribute__((address_space(3))) void*)(lp), 16, 0, 0)

// ---------------------------------------------------------------------------
// GEMM: C[M,N] = A[M,K] @ Bt[N,K]^T   (A, Bt bf16 row-major; Bt is B^T)
// BM=128, BK=64, BN in {128,64}. 256 threads = 4 waves (2x2 wave grid,
// wave tile 64 x BN/2). global_load_lds(16B) staging; LDS slot-XOR swizzle
// (slot ^= row&7) applied on the GLOBAL source + on the ds_read address so
// the linear LDS dest of global_load_lds still works (guide §5/m173/m201).
// OM: 0 = bf16 C[M,N]; 1 = bf16 C[N,M] (transposed); 2 = fp32 C[M,N].
// CAUSAL: skip tiles fully above the diagonal (rowBase = global row of A[0]).
// KCAP:   k-loop capped at rowBase+bm+BM (PV: P cols beyond are zero).
// SILU:   apply x*sigmoid(x) in epilogue.
// ---------------------------------------------------------------------------
template<int BN, int OM, bool CAUSAL, bool KCAP, bool SILU>
__global__ __launch_bounds__(256, 2)
void gemm_bt(const unsigned short* __restrict__ A,
             const unsigned short* __restrict__ Bt,
             void* __restrict__ Cp,
             int M, int N, int K, float scale, int rowBase)
{
    constexpr int BM = 128, BK = 64;
    constexpr int NF = BN / 32;           // b-frags per wave
    __shared__ __align__(16) unsigned short As[BM * BK];
    __shared__ __align__(16) unsigned short Bs[BN * BK];

    const int t = threadIdx.x, lane = t & 63, w = t >> 6;
    const int wr = w >> 1, wc = w & 1;
    const int ln15 = lane & 15, hi = lane >> 4;
    const int bm = blockIdx.y * BM, bn = blockIdx.x * BN;

    if (CAUSAL && bn > rowBase + bm + (BM - 1)) return;   // fully-masked tile
    int Keff = K;
    if (KCAP) { int kc = rowBase + bm + BM; Keff = kc < K ? kc : K; }

    f32x4 acc[4][NF] = {};

    for (int k0 = 0; k0 < Keff; k0 += BK) {
        // ---- stage A tile (128 x 64 bf16 = 16 KB = 1024 x 16B chunks)
        #pragma unroll
        for (int i = 0; i < 4; ++i) {
            int c = t + 256 * i;
            int r = c >> 3, q = (c & 7) ^ (r & 7);        // pre-swizzled src
            GLOAD16(A + (size_t)(bm + r) * K + k0 + q * 8,
                    (unsigned short*)As + c * 8);
        }
        // ---- stage B tile (BN x 64)
        #pragma unroll
        for (int i = 0; i < BN / 32; ++i) {
            int c = t + 256 * i;
            int r = c >> 3, q = (c & 7) ^ (r & 7);
            GLOAD16(Bt + (size_t)(bn + r) * K + k0 + q * 8,
                    (unsigned short*)Bs + c * 8);
        }
        __syncthreads();

        #pragma unroll
        for (int kk = 0; kk < 2; ++kk) {
            short8 a[4], b[NF];
            #pragma unroll
            for (int m = 0; m < 4; ++m) {
                int r = wr * 64 + m * 16 + ln15;
                int s = (kk * 4 + hi) ^ (r & 7);          // swizzled read
                a[m] = *(const short8*)(As + r * 64 + s * 8);
            }
            #pragma unroll
            for (int n = 0; n < NF; ++n) {
                int r = wc * (BN / 2) + n * 16 + ln15;
                int s = (kk * 4 + hi) ^ (r & 7);
                b[n] = *(const short8*)(Bs + r * 64 + s * 8);
            }
            #pragma unroll
            for (int m = 0; m < 4; ++m)
                #pragma unroll
                for (int n = 0; n < NF; ++n)
                    acc[m][n] = MFMA_BF16(a[m], b[n], acc[m][n], 0, 0, 0);
        }
        __syncthreads();
    }

    // ---- epilogue: C/D layout col = lane&15, row = (lane>>4)*4 + j
    #pragma unroll
    for (int m = 0; m < 4; ++m)
        #pragma unroll
        for (int n = 0; n < NF; ++n)
            #pragma unroll
            for (int j = 0; j < 4; ++j) {
                int row = bm + wr * 64 + m * 16 + hi * 4 + j;
                int col = bn + wc * (BN / 2) + n * 16 + ln15;
                float v = acc[m][n][j] * scale;
                if (SILU) v = v / (1.0f + __expf(-v));
                if (OM == 0)
                    ((unsigned short*)Cp)[(size_t)row * N + col] = f2bf(v);
                else if (OM == 1)
                    ((unsigned short*)Cp)[(size_t)col * M + row] = f2bf(v);
                else
                    ((float*)Cp)[(size_t)row * N + col] = v;
            }
}

// ---------------------------------------------------------------------------
// Row softmax over a 2048-row band of S (bf16 [2048][8192]), in place.
// Row r: valid cols [0, grow], zero-fill to the 128 boundary Kcap (so the
// K-capped PV GEMM sees zeros above the diagonal); cols >= Kcap untouched.
// One block per row, 256 threads, row held in registers (32 f32/thread).
// ---------------------------------------------------------------------------
__global__ __launch_bounds__(256)
void softmax_rows(unsigned short* __restrict__ S, int rowBase)
{
    __shared__ float red[4];
    const int r = blockIdx.x;
    const int grow = rowBase + r;
    const int Kcap = ((grow >> 7) + 1) << 7;
    unsigned short* row = S + (size_t)r * SEQ;
    const int t = threadIdx.x, lane = t & 63, w = t >> 6;

    float v[4][8];
    float mx = -1e30f;
    #pragma unroll
    for (int i = 0; i < 4; ++i) {
        int c0 = (i * 256 + t) * 8;
        if (c0 < Kcap) {
            short8 s8 = *(const short8*)(row + c0);
            #pragma unroll
            for (int j = 0; j < 8; ++j) {
                float f = bf2f((unsigned short)s8[j]);
                v[i][j] = (c0 + j <= grow) ? f : -1e30f;
                mx = fmaxf(mx, v[i][j]);
            }
        } else {
            #pragma unroll
            for (int j = 0; j < 8; ++j) v[i][j] = -1e30f;
        }
    }
    #pragma unroll
    for (int off = 32; off >= 1; off >>= 1)
        mx = fmaxf(mx, __shfl_xor(mx, off, 64));
    if (lane == 0) red[w] = mx;
    __syncthreads();
    mx = fmaxf(fmaxf(red[0], red[1]), fmaxf(red[2], red[3]));
    __syncthreads();

    float sum = 0.f;
    #pragma unroll
    for (int i = 0; i < 4; ++i)
        #pragma unroll
        for (int j = 0; j < 8; ++j) {
            float p = (v[i][j] > -1e29f) ? __expf(v[i][j] - mx) : 0.f;
            v[i][j] = p;
            sum += p;
        }
    #pragma unroll
    for (int off = 32; off >= 1; off >>= 1)
        sum += __shfl_xor(sum, off, 64);
    if (lane == 0) red[w] = sum;
    __syncthreads();
    sum = red[0] + red[1] + red[2] + red[3];
    const float inv = 1.0f / sum;

    #pragma unroll
    for (int i = 0; i < 4; ++i) {
        int c0 = (i * 256 + t) * 8;
        if (c0 < Kcap) {
            short8 o;
            #pragma unroll
            for (int j = 0; j < 8; ++j) o[j] = (short)f2bf(v[i][j] * inv);
            *(short8*)(row + c0) = o;
        }
    }
}

// ---------------------------------------------------------------------------
// fp32 -> bf16 bulk convert (8 elems/thread, vectorized)
// ---------------------------------------------------------------------------
__global__ __launch_bounds__(256)
void cvt_bf16(const float* __restrict__ X, unsigned short* __restrict__ Y)
{
    int i = (blockIdx.x * 256 + threadIdx.x) * 8;
    f32x4 v0 = *(const f32x4*)(X + i);
    f32x4 v1 = *(const f32x4*)(X + i + 4);
    short8 o = { (short)f2bf(v0[0]), (short)f2bf(v0[1]),
                 (short)f2bf(v0[2]), (short)f2bf(v0[3]),
                 (short)f2bf(v1[0]), (short)f2bf(v1[1]),
                 (short)f2bf(v1[2]), (short)f2bf(v1[3]) };
    *(short8*)(Y + i) = o;
}

// ---------------------------------------------------------------------------
// 1024x1024 fp32 W -> bf16 W^T (LDS-tiled transpose, coalesced both sides)
// ---------------------------------------------------------------------------
__global__ __launch_bounds__(256)
void twT(const float* __restrict__ W, unsigned short* __restrict__ WT)
{
    __shared__ float tile[64][65];
    const int bx = blockIdx.x * 64, by = blockIdx.y * 64;
    const int t = threadIdx.x, rr = t >> 4, c4 = (t & 15) * 4;
    #pragma unroll
    for (int i = 0; i < 4; ++i) {
        int r = rr + i * 16;
        f32x4 v = *(const f32x4*)(W + (size_t)(by + r) * DIM + bx + c4);
        tile[r][c4 + 0] = v[0]; tile[r][c4 + 1] = v[1];
        tile[r][c4 + 2] = v[2]; tile[r][c4 + 3] = v[3];
    }
    __syncthreads();
    #pragma unroll
    for (int i = 0; i < 4; ++i) {
        int r = rr + i * 16;                           // WT row = bx + r
        us4 o = { f2bf(tile[c4 + 0][r]), f2bf(tile[c4 + 1][r]),
                  f2bf(tile[c4 + 2][r]), f2bf(tile[c4 + 3][r]) };
        *(us4*)(WT + (size_t)(bx + r) * DIM + by + c4) = o;
    }
}

// ---------------------------------------------------------------------------
extern "C" void kernel_launch(void* const* d_in, const int* in_sizes, int n_in,
                              void* d_out, int out_size, void* d_ws, size_t ws_size,
                              hipStream_t stream)
{
    const float* x   = (const float*)d_in[0];
    const float* wq  = (const float*)d_in[1];
    const float* wk  = (const float*)d_in[2];
    const float* wv1 = (const float*)d_in[3];
    const float* wv2 = (const float*)d_in[4];

    // ws (48 MB, proven): Q/H bf16 [S,D] | K bf16 [S,D] | V^T bf16 [D,S]
    unsigned short* qbuf  = (unsigned short*)d_ws;
    unsigned short* kbuf  = qbuf + (size_t)SEQ * DIM;
    unsigned short* vtbuf = kbuf + (size_t)SEQ * DIM;

    // d_out (32 MB) as staging: xb + wT's during projections, then S bands.
    unsigned short* xb    = (unsigned short*)d_out;
    unsigned short* wqT   = xb + (size_t)SEQ * DIM;
    unsigned short* wkT   = wqT + DIM * DIM;
    unsigned short* wv1T  = wkT + DIM * DIM;
    unsigned short* Sband = (unsigned short*)d_out;

    dim3 tg(16, 16);
    cvt_bf16<<<SEQ * DIM / 2048, 256, 0, stream>>>(x, xb);
    twT<<<tg, 256, 0, stream>>>(wq,  wqT);
    twT<<<tg, 256, 0, stream>>>(wk,  wkT);
    twT<<<tg, 256, 0, stream>>>(wv1, wv1T);

    // Projections: Q, K as [S,D]; V stored transposed [D,S].
    dim3 gproj(DIM / 128, SEQ / 128);
    gemm_bt<128,0,false,false,false><<<gproj, 256, 0, stream>>>(
        xb, wqT,  qbuf,  SEQ, DIM, DIM, 1.0f, 0);
    gemm_bt<128,0,false,false,false><<<gproj, 256, 0, stream>>>(
        xb, wkT,  kbuf,  SEQ, DIM, DIM, 1.0f, 0);
    gemm_bt<128,1,false,false,false><<<gproj, 256, 0, stream>>>(
        xb, wv1T, vtbuf, SEQ, DIM, DIM, 1.0f, 0);

    // Banded attention: S-band (2048x8192 bf16, 32 MB) lives in d_out.
    constexpr int BAND = 2048;
    for (int b = 0; b < 4; ++b) {
        const int rb = b * BAND;
        dim3 gq(SEQ / 128, BAND / 128);     // 64 x 16
        gemm_bt<128,0,true,false,false><<<gq, 256, 0, stream>>>(
            qbuf + (size_t)rb * DIM, kbuf, Sband, BAND, SEQ, DIM, 0.03125f, rb);
        if (b == 3)  // K no longer needed: stage wv2^T into kbuf
            twT<<<tg, 256, 0, stream>>>(wv2, kbuf);
        softmax_rows<<<BAND, 256, 0, stream>>>(Sband, rb);
        dim3 gpv(DIM / 64, BAND / 128);     // 16 x 16 (256 blocks)
        gemm_bt<64,0,false,true,true><<<gpv, 256, 0, stream>>>(
            Sband, vtbuf, qbuf + (size_t)rb * DIM, BAND, DIM, SEQ, 1.0f, rb);
    }

    // Output projection: silu(hidden) @ wv2 -> fp32 d_out
    gemm_bt<128,2,false,false,false><<<gproj, 256, 0, stream>>>(
        qbuf, kbuf, d_out, SEQ, DIM, DIM, 1.0f, 0);
}

// Round 6
// 448.475 us; speedup vs baseline: 5.3744x; 1.1679x over previous
//
#include <hip/hip_runtime.h>
#include <hip/hip_bf16.h>
#include <cstdint>
#include <cstddef>

constexpr int SEQ = 8192;
constexpr int DIM = 1024;

typedef __attribute__((ext_vector_type(8))) short short8;   // bf16x8 MFMA frag
typedef __attribute__((ext_vector_type(4))) float f32x4;    // fp32x4 acc frag
typedef __attribute__((ext_vector_type(4))) unsigned short us4;

#define MFMA_BF16 __builtin_amdgcn_mfma_f32_16x16x32_bf16

static __device__ __forceinline__ unsigned short f2bf(float f) {
    uint32_t u = __builtin_bit_cast(uint32_t, f);
    u += 0x7FFFu + ((u >> 16) & 1u);      // round-to-nearest-even
    return (unsigned short)(u >> 16);
}
static __device__ __forceinline__ float bf2f(unsigned short h) {
    uint32_t u = ((uint32_t)h) << 16;
    return __builtin_bit_cast(float, u);
}

#define GLOAD16(gp, lp) __builtin_amdgcn_global_load_lds(                      \
    (const __attribute__((address_space(1))) void*)(gp),                       \
    (__attribute__((address_space(3))) void*)(lp), 16, 0, 0)

// ---------------------------------------------------------------------------
// GEMM: C[M,N] = A[M,K] @ Bt[N,K]^T   (A, Bt bf16 row-major; Bt is B^T)
// BM=128, BK=64, BN in {128,64}. 256 threads = 4 waves (2x2 wave grid).
// 2-phase double-buffered LDS pipeline: issue next tile's global_load_lds
// BEFORE computing current tile; single __syncthreads per K-step (its
// implicit vmcnt(0) drain covers the prefetch). XOR slot-swizzle on the
// global source + ds_read address (linear LDS dest for global_load_lds).
// OM: 0 = bf16 C[M,N]; 1 = bf16 C[N,M]; 2 = fp32 C[M,N];
//     3 = fp32 partial at Cp + blockIdx.z*M*N (split-K).
// CAUSAL: skip tiles fully above diagonal. KCAP: k capped at rowBase+bm+BM.
// SPLITK: this block covers k in [z*CH, min(Keff, z*CH+CH)).
// ---------------------------------------------------------------------------
template<int BN, int OM, bool CAUSAL, bool KCAP, bool SILU, bool SPLITK>
__global__ __launch_bounds__(256, 2)
void gemm_bt(const unsigned short* __restrict__ A,
             const unsigned short* __restrict__ Bt,
             void* __restrict__ Cp,
             int M, int N, int K, float scale, int rowBase, int CH)
{
    constexpr int BM = 128, BK = 64;
    constexpr int NF = BN / 32;           // b-frags per wave
    __shared__ __align__(16) unsigned short As[2][BM * BK];
    __shared__ __align__(16) unsigned short Bs[2][BN * BK];

    const int t = threadIdx.x, lane = t & 63, w = t >> 6;
    const int wr = w >> 1, wc = w & 1;
    const int ln15 = lane & 15, hi = lane >> 4;
    const int bm = blockIdx.y * BM, bn = blockIdx.x * BN;

    if (CAUSAL && bn > rowBase + bm + (BM - 1)) return;   // fully-masked tile
    int Keff = K;
    if (KCAP) { int kc = rowBase + bm + BM; Keff = kc < K ? kc : K; }
    int kbeg = 0, kend = Keff;
    if (SPLITK) {
        kbeg = blockIdx.z * CH;
        int ke = kbeg + CH;
        kend = ke < Keff ? ke : Keff;
        if (kbeg >= kend) return;          // nothing in this split
    }

#define STAGE_TILES(buf, k0) do {                                              \
        _Pragma("unroll")                                                      \
        for (int i = 0; i < 4; ++i) {                                          \
            int c = t + 256 * i;                                               \
            int r = c >> 3, q = (c & 7) ^ (r & 7);                             \
            GLOAD16(A + (size_t)(bm + r) * K + (k0) + q * 8,                   \
                    &As[buf][c * 8]);                                          \
        }                                                                      \
        _Pragma("unroll")                                                      \
        for (int i = 0; i < BN / 32; ++i) {                                    \
            int c = t + 256 * i;                                               \
            int r = c >> 3, q = (c & 7) ^ (r & 7);                             \
            GLOAD16(Bt + (size_t)(bn + r) * K + (k0) + q * 8,                  \
                    &Bs[buf][c * 8]);                                          \
        }                                                                      \
    } while (0)

    f32x4 acc[4][NF] = {};

    STAGE_TILES(0, kbeg);
    __syncthreads();                       // drains prologue loads
    int cur = 0;
    for (int k0 = kbeg; k0 < kend; k0 += BK) {
        if (k0 + BK < kend) STAGE_TILES(cur ^ 1, k0 + BK);   // prefetch next

        #pragma unroll
        for (int kk = 0; kk < 2; ++kk) {
            short8 a[4], b[NF];
            #pragma unroll
            for (int m = 0; m < 4; ++m) {
                int r = wr * 64 + m * 16 + ln15;
                int s = (kk * 4 + hi) ^ (r & 7);          // swizzled read
                a[m] = *(const short8*)(&As[cur][r * 64 + s * 8]);
            }
            #pragma unroll
            for (int n = 0; n < NF; ++n) {
                int r = wc * (BN / 2) + n * 16 + ln15;
                int s = (kk * 4 + hi) ^ (r & 7);
                b[n] = *(const short8*)(&Bs[cur][r * 64 + s * 8]);
            }
            #pragma unroll
            for (int m = 0; m < 4; ++m)
                #pragma unroll
                for (int n = 0; n < NF; ++n)
                    acc[m][n] = MFMA_BF16(a[m], b[n], acc[m][n], 0, 0, 0);
        }
        __syncthreads();                   // drains prefetch + barrier
        cur ^= 1;
    }
#undef STAGE_TILES

    // ---- epilogue: C/D layout col = lane&15, row = (lane>>4)*4 + j
    float* Pz = (OM == 3)
        ? (float*)Cp + (size_t)blockIdx.z * M * N : nullptr;
    #pragma unroll
    for (int m = 0; m < 4; ++m)
        #pragma unroll
        for (int n = 0; n < NF; ++n)
            #pragma unroll
            for (int j = 0; j < 4; ++j) {
                int row = bm + wr * 64 + m * 16 + hi * 4 + j;
                int col = bn + wc * (BN / 2) + n * 16 + ln15;
                float v = acc[m][n][j] * scale;
                if (SILU) v = v / (1.0f + __expf(-v));
                if (OM == 0)
                    ((unsigned short*)Cp)[(size_t)row * N + col] = f2bf(v);
                else if (OM == 1)
                    ((unsigned short*)Cp)[(size_t)col * M + row] = f2bf(v);
                else if (OM == 2)
                    ((float*)Cp)[(size_t)row * N + col] = v;
                else
                    Pz[(size_t)row * N + col] = v;
            }
}

// ---------------------------------------------------------------------------
// Split-K reduction: sum nvalid fp32 partials, SiLU, bf16 -> out (band rows).
// nvalid per row = ceil(Keff_block / CH), matching the PV split-skip rule.
// ---------------------------------------------------------------------------
__global__ __launch_bounds__(256)
void reduce_silu(const float* __restrict__ part, unsigned short* __restrict__ out,
                 int nsplit, int CH, int rowBase)
{
    const size_t idx = ((size_t)blockIdx.x * 256 + threadIdx.x) * 8;
    const int r = (int)(idx >> 10);                 // DIM = 1024
    int keb = rowBase + ((r >> 7) << 7) + 128;      // Keff of r's PV block-row
    if (keb > SEQ) keb = SEQ;
    int nv = (keb + CH - 1) / CH;
    if (nv > nsplit) nv = nsplit;

    f32x4 s0 = {}, s1 = {};
    for (int s = 0; s < nv; ++s) {
        const float* p = part + (size_t)s * (2048 * 1024) + idx;
        s0 += *(const f32x4*)p;
        s1 += *(const f32x4*)(p + 4);
    }
    short8 o;
    #pragma unroll
    for (int j = 0; j < 4; ++j) {
        float v = s0[j];
        o[j] = (short)f2bf(v / (1.0f + __expf(-v)));
    }
    #pragma unroll
    for (int j = 0; j < 4; ++j) {
        float v = s1[j];
        o[4 + j] = (short)f2bf(v / (1.0f + __expf(-v)));
    }
    *(short8*)(out + idx) = o;
}

// ---------------------------------------------------------------------------
// Row softmax over a 2048-row band of S (bf16 [2048][8192]), in place.
// Valid cols [0, grow], zero-fill to the 128 boundary Kcap; cols >= Kcap
// untouched (PV's K-cap never reads them).
// ---------------------------------------------------------------------------
__global__ __launch_bounds__(256)
void softmax_rows(unsigned short* __restrict__ S, int rowBase)
{
    __shared__ float red[4];
    const int r = blockIdx.x;
    const int grow = rowBase + r;
    const int Kcap = ((grow >> 7) + 1) << 7;
    unsigned short* row = S + (size_t)r * SEQ;
    const int t = threadIdx.x, lane = t & 63, w = t >> 6;

    float v[4][8];
    float mx = -1e30f;
    #pragma unroll
    for (int i = 0; i < 4; ++i) {
        int c0 = (i * 256 + t) * 8;
        if (c0 < Kcap) {
            short8 s8 = *(const short8*)(row + c0);
            #pragma unroll
            for (int j = 0; j < 8; ++j) {
                float f = bf2f((unsigned short)s8[j]);
                v[i][j] = (c0 + j <= grow) ? f : -1e30f;
                mx = fmaxf(mx, v[i][j]);
            }
        } else {
            #pragma unroll
            for (int j = 0; j < 8; ++j) v[i][j] = -1e30f;
        }
    }
    #pragma unroll
    for (int off = 32; off >= 1; off >>= 1)
        mx = fmaxf(mx, __shfl_xor(mx, off, 64));
    if (lane == 0) red[w] = mx;
    __syncthreads();
    mx = fmaxf(fmaxf(red[0], red[1]), fmaxf(red[2], red[3]));
    __syncthreads();

    float sum = 0.f;
    #pragma unroll
    for (int i = 0; i < 4; ++i)
        #pragma unroll
        for (int j = 0; j < 8; ++j) {
            float p = (v[i][j] > -1e29f) ? __expf(v[i][j] - mx) : 0.f;
            v[i][j] = p;
            sum += p;
        }
    #pragma unroll
    for (int off = 32; off >= 1; off >>= 1)
        sum += __shfl_xor(sum, off, 64);
    if (lane == 0) red[w] = sum;
    __syncthreads();
    sum = red[0] + red[1] + red[2] + red[3];
    const float inv = 1.0f / sum;

    #pragma unroll
    for (int i = 0; i < 4; ++i) {
        int c0 = (i * 256 + t) * 8;
        if (c0 < Kcap) {
            short8 o;
            #pragma unroll
            for (int j = 0; j < 8; ++j) o[j] = (short)f2bf(v[i][j] * inv);
            *(short8*)(row + c0) = o;
        }
    }
}

// ---------------------------------------------------------------------------
__global__ __launch_bounds__(256)
void cvt_bf16(const float* __restrict__ X, unsigned short* __restrict__ Y)
{
    int i = (blockIdx.x * 256 + threadIdx.x) * 8;
    f32x4 v0 = *(const f32x4*)(X + i);
    f32x4 v1 = *(const f32x4*)(X + i + 4);
    short8 o = { (short)f2bf(v0[0]), (short)f2bf(v0[1]),
                 (short)f2bf(v0[2]), (short)f2bf(v0[3]),
                 (short)f2bf(v1[0]), (short)f2bf(v1[1]),
                 (short)f2bf(v1[2]), (short)f2bf(v1[3]) };
    *(short8*)(Y + i) = o;
}

// ---------------------------------------------------------------------------
__global__ __launch_bounds__(256)
void twT(const float* __restrict__ W, unsigned short* __restrict__ WT)
{
    __shared__ float tile[64][65];
    const int bx = blockIdx.x * 64, by = blockIdx.y * 64;
    const int t = threadIdx.x, rr = t >> 4, c4 = (t & 15) * 4;
    #pragma unroll
    for (int i = 0; i < 4; ++i) {
        int r = rr + i * 16;
        f32x4 v = *(const f32x4*)(W + (size_t)(by + r) * DIM + bx + c4);
        tile[r][c4 + 0] = v[0]; tile[r][c4 + 1] = v[1];
        tile[r][c4 + 2] = v[2]; tile[r][c4 + 3] = v[3];
    }
    __syncthreads();
    #pragma unroll
    for (int i = 0; i < 4; ++i) {
        int r = rr + i * 16;                           // WT row = bx + r
        us4 o = { f2bf(tile[c4 + 0][r]), f2bf(tile[c4 + 1][r]),
                  f2bf(tile[c4 + 2][r]), f2bf(tile[c4 + 3][r]) };
        *(us4*)(WT + (size_t)(bx + r) * DIM + by + c4) = o;
    }
}

// ---------------------------------------------------------------------------
extern "C" void kernel_launch(void* const* d_in, const int* in_sizes, int n_in,
                              void* d_out, int out_size, void* d_ws, size_t ws_size,
                              hipStream_t stream)
{
    const float* x   = (const float*)d_in[0];
    const float* wq  = (const float*)d_in[1];
    const float* wk  = (const float*)d_in[2];
    const float* wv1 = (const float*)d_in[3];
    const float* wv2 = (const float*)d_in[4];

    // ws: Q/H bf16 [S,D] | K bf16 [S,D] | V^T bf16 [D,S] | split-K partials
    const size_t BUF = (size_t)SEQ * DIM * sizeof(unsigned short);  // 16 MiB
    unsigned short* qbuf  = (unsigned short*)d_ws;
    unsigned short* kbuf  = qbuf + (size_t)SEQ * DIM;
    unsigned short* vtbuf = kbuf + (size_t)SEQ * DIM;
    float* part = (float*)((char*)d_ws + 3 * BUF);
    const size_t PSZ = (size_t)2048 * 1024 * sizeof(float);         // 8 MiB
    int nsplit = 0;
    if (ws_size >= 3 * BUF + 2 * PSZ)
        nsplit = (int)(((ws_size - 3 * BUF) / PSZ) < 4
                        ? (ws_size - 3 * BUF) / PSZ : 4);

    // d_out staging: xb + wT's during projections, then S bands.
    unsigned short* xb    = (unsigned short*)d_out;
    unsigned short* wqT   = xb + (size_t)SEQ * DIM;
    unsigned short* wkT   = wqT + DIM * DIM;
    unsigned short* wv1T  = wkT + DIM * DIM;
    unsigned short* Sband = (unsigned short*)d_out;

    dim3 tg(16, 16);
    cvt_bf16<<<SEQ * DIM / 2048, 256, 0, stream>>>(x, xb);
    twT<<<tg, 256, 0, stream>>>(wq,  wqT);
    twT<<<tg, 256, 0, stream>>>(wk,  wkT);
    twT<<<tg, 256, 0, stream>>>(wv1, wv1T);

    dim3 gproj(DIM / 128, SEQ / 128);
    gemm_bt<128,0,false,false,false,false><<<gproj, 256, 0, stream>>>(
        xb, wqT,  qbuf,  SEQ, DIM, DIM, 1.0f, 0, 0);
    gemm_bt<128,0,false,false,false,false><<<gproj, 256, 0, stream>>>(
        xb, wkT,  kbuf,  SEQ, DIM, DIM, 1.0f, 0, 0);
    gemm_bt<128,1,false,false,false,false><<<gproj, 256, 0, stream>>>(
        xb, wv1T, vtbuf, SEQ, DIM, DIM, 1.0f, 0, 0);

    constexpr int BAND = 2048;
    for (int b = 0; b < 4; ++b) {
        const int rb = b * BAND;
        const int ncol = (rb + BAND) / 128;        // prune all-masked columns
        dim3 gq(ncol, BAND / 128);
        gemm_bt<128,0,true,false,false,false><<<gq, 256, 0, stream>>>(
            qbuf + (size_t)rb * DIM, kbuf, Sband, BAND, SEQ, DIM, 0.03125f, rb, 0);
        if (b == 3)  // K no longer needed: stage wv2^T into kbuf
            twT<<<tg, 256, 0, stream>>>(wv2, kbuf);
        softmax_rows<<<BAND, 256, 0, stream>>>(Sband, rb);
        if (nsplit >= 2) {
            const int CH = (((rb + BAND) / nsplit + 63) / 64) * 64;
            dim3 gpv(DIM / 64, BAND / 128, nsplit);
            gemm_bt<64,3,false,true,false,true><<<gpv, 256, 0, stream>>>(
                Sband, vtbuf, part, BAND, DIM, SEQ, 1.0f, rb, CH);
            reduce_silu<<<BAND * DIM / 2048, 256, 0, stream>>>(
                part, qbuf + (size_t)rb * DIM, nsplit, CH, rb);
        } else {
            dim3 gpv(DIM / 64, BAND / 128);
            gemm_bt<64,0,false,true,true,false><<<gpv, 256, 0, stream>>>(
                Sband, vtbuf, qbuf + (size_t)rb * DIM, BAND, DIM, SEQ, 1.0f, rb, 0);
        }
    }

    gemm_bt<128,2,false,false,false,false><<<gproj, 256, 0, stream>>>(
        qbuf, kbuf, d_out, SEQ, DIM, DIM, 1.0f, 0, 0);
}

// Round 7
// 421.714 us; speedup vs baseline: 5.7155x; 1.0635x over previous
//
#include <hip/hip_runtime.h>
#include <hip/hip_bf16.h>
#include <cstdint>
#include <cstddef>

constexpr int SEQ = 8192;
constexpr int DIM = 1024;

typedef __attribute__((ext_vector_type(8))) short short8;   // bf16x8 MFMA frag
typedef __attribute__((ext_vector_type(4))) float f32x4;    // fp32x4 acc frag
typedef __attribute__((ext_vector_type(4))) unsigned short us4;

#define MFMA_BF16 __builtin_amdgcn_mfma_f32_16x16x32_bf16

static __device__ __forceinline__ unsigned short f2bf(float f) {
    uint32_t u = __builtin_bit_cast(uint32_t, f);
    u += 0x7FFFu + ((u >> 16) & 1u);      // round-to-nearest-even
    return (unsigned short)(u >> 16);
}
static __device__ __forceinline__ float bf2f(unsigned short h) {
    uint32_t u = ((uint32_t)h) << 16;
    return __builtin_bit_cast(float, u);
}

#define GLOAD16(gp, lp) __builtin_amdgcn_global_load_lds(                      \
    (const __attribute__((address_space(1))) void*)(gp),                       \
    (__attribute__((address_space(3))) void*)(lp), 16, 0, 0)

// ---------------------------------------------------------------------------
// GEMM: C[M,N] = A[M,K] @ Bt[N,K]^T   (A, Bt bf16 row-major; Bt is B^T)
// BM=128, BK=64, BN=128. 256 threads = 4 waves (2x2 wave grid).
// Counted-vmcnt pipelined loop (T3/T4-lite): raw s_barrier (no implicit
// vmcnt drain, unlike __syncthreads) + ONE manual vmcnt(0) per K-step
// placed AFTER the MFMA phase, so prefetch gloads stay in flight across
// the whole compute phase. setprio(1) around the MFMA cluster (T5).
// XOR slot-swizzle on the global source + ds_read address (bank-conflict
// free, measured 0 conflicts). OM: 0=bf16 C[M,N]; 1=bf16 C[N,M];
// 2=fp32 C[M,N]; 3=fp32 partial at Cp + z*M*N (split-K).
// ---------------------------------------------------------------------------
template<int OM, bool CAUSAL, bool KCAP, bool SILU, bool SPLITK>
__global__ __launch_bounds__(256, 2)
void gemm_bt(const unsigned short* __restrict__ A,
             const unsigned short* __restrict__ Bt,
             void* __restrict__ Cp,
             int M, int N, int K, float scale, int rowBase, int CH)
{
    constexpr int BM = 128, BK = 64, BN = 128;
    constexpr int NF = BN / 32;           // 4 b-frags per wave
    __shared__ __align__(16) unsigned short As[2][BM * BK];
    __shared__ __align__(16) unsigned short Bs[2][BN * BK];

    const int t = threadIdx.x, lane = t & 63, w = t >> 6;
    const int wr = w >> 1, wc = w & 1;
    const int ln15 = lane & 15, hi = lane >> 4;
    const int bm = blockIdx.y * BM, bn = blockIdx.x * BN;

    if (CAUSAL && bn > rowBase + bm + (BM - 1)) return;   // fully-masked tile
    int Keff = K;
    if (KCAP) { int kc = rowBase + bm + BM; Keff = kc < K ? kc : K; }
    int kbeg = 0, kend = Keff;
    if (SPLITK) {
        kbeg = blockIdx.z * CH;
        int ke = kbeg + CH;
        kend = ke < Keff ? ke : Keff;
        if (kbeg >= kend) return;          // nothing in this split
    }

#define STAGE_TILES(buf, k0) do {                                              \
        _Pragma("unroll")                                                      \
        for (int i = 0; i < 4; ++i) {                                          \
            int c = t + 256 * i;                                               \
            int r = c >> 3, q = (c & 7) ^ (r & 7);                             \
            GLOAD16(A + (size_t)(bm + r) * K + (k0) + q * 8,                   \
                    &As[buf][c * 8]);                                          \
        }                                                                      \
        _Pragma("unroll")                                                      \
        for (int i = 0; i < 4; ++i) {                                          \
            int c = t + 256 * i;                                               \
            int r = c >> 3, q = (c & 7) ^ (r & 7);                             \
            GLOAD16(Bt + (size_t)(bn + r) * K + (k0) + q * 8,                  \
                    &Bs[buf][c * 8]);                                          \
        }                                                                      \
    } while (0)

    f32x4 acc[4][NF] = {};

    STAGE_TILES(0, kbeg);
    asm volatile("s_waitcnt vmcnt(0)" ::: "memory");
    __builtin_amdgcn_s_barrier();
    int cur = 0;
    for (int k0 = kbeg; k0 < kend; k0 += BK) {
        if (k0 + BK < kend) STAGE_TILES(cur ^ 1, k0 + BK);   // prefetch next

        #pragma unroll
        for (int kk = 0; kk < 2; ++kk) {
            short8 a[4], b[NF];
            #pragma unroll
            for (int m = 0; m < 4; ++m) {
                int r = wr * 64 + m * 16 + ln15;
                int s = (kk * 4 + hi) ^ (r & 7);          // swizzled read
                a[m] = *(const short8*)(&As[cur][r * 64 + s * 8]);
            }
            #pragma unroll
            for (int n = 0; n < NF; ++n) {
                int r = wc * 64 + n * 16 + ln15;
                int s = (kk * 4 + hi) ^ (r & 7);
                b[n] = *(const short8*)(&Bs[cur][r * 64 + s * 8]);
            }
            __builtin_amdgcn_s_setprio(1);
            #pragma unroll
            for (int m = 0; m < 4; ++m)
                #pragma unroll
                for (int n = 0; n < NF; ++n)
                    acc[m][n] = MFMA_BF16(a[m], b[n], acc[m][n], 0, 0, 0);
            __builtin_amdgcn_s_setprio(0);
        }
        // own prefetch landed; all waves done reading buf[cur] after barrier
        asm volatile("s_waitcnt vmcnt(0)" ::: "memory");
        __builtin_amdgcn_s_barrier();
        cur ^= 1;
    }
#undef STAGE_TILES

    // ---- epilogue: C/D layout col = lane&15, row = (lane>>4)*4 + j
    float* Pz = (OM == 3)
        ? (float*)Cp + (size_t)blockIdx.z * M * N : nullptr;
    #pragma unroll
    for (int m = 0; m < 4; ++m)
        #pragma unroll
        for (int n = 0; n < NF; ++n)
            #pragma unroll
            for (int j = 0; j < 4; ++j) {
                int row = bm + wr * 64 + m * 16 + hi * 4 + j;
                int col = bn + wc * 64 + n * 16 + ln15;
                float v = acc[m][n][j] * scale;
                if (SILU) v = v / (1.0f + __expf(-v));
                if (OM == 0)
                    ((unsigned short*)Cp)[(size_t)row * N + col] = f2bf(v);
                else if (OM == 1)
                    ((unsigned short*)Cp)[(size_t)col * M + row] = f2bf(v);
                else if (OM == 2)
                    ((float*)Cp)[(size_t)row * N + col] = v;
                else
                    Pz[(size_t)row * N + col] = v;
            }
}

// ---------------------------------------------------------------------------
// Split-K reduction: sum nvalid fp32 partials, SiLU, bf16 -> out (band rows).
// ---------------------------------------------------------------------------
__global__ __launch_bounds__(256)
void reduce_silu(const float* __restrict__ part, unsigned short* __restrict__ out,
                 int nsplit, int CH, int rowBase)
{
    const size_t idx = ((size_t)blockIdx.x * 256 + threadIdx.x) * 8;
    const int r = (int)(idx >> 10);                 // DIM = 1024
    int keb = rowBase + ((r >> 7) << 7) + 128;      // Keff of r's PV block-row
    if (keb > SEQ) keb = SEQ;
    int nv = (keb + CH - 1) / CH;
    if (nv > nsplit) nv = nsplit;

    f32x4 s0 = {}, s1 = {};
    for (int s = 0; s < nv; ++s) {
        const float* p = part + (size_t)s * (2048 * 1024) + idx;
        s0 += *(const f32x4*)p;
        s1 += *(const f32x4*)(p + 4);
    }
    short8 o;
    #pragma unroll
    for (int j = 0; j < 4; ++j) {
        float v = s0[j];
        o[j] = (short)f2bf(v / (1.0f + __expf(-v)));
    }
    #pragma unroll
    for (int j = 0; j < 4; ++j) {
        float v = s1[j];
        o[4 + j] = (short)f2bf(v / (1.0f + __expf(-v)));
    }
    *(short8*)(out + idx) = o;
}

// ---------------------------------------------------------------------------
// Row softmax over a 2048-row band of S (bf16 [2048][8192]), in place.
// Valid cols [0, grow], zero-fill to the 128 boundary Kcap.
// ---------------------------------------------------------------------------
__global__ __launch_bounds__(256)
void softmax_rows(unsigned short* __restrict__ S, int rowBase)
{
    __shared__ float red[4];
    const int r = blockIdx.x;
    const int grow = rowBase + r;
    const int Kcap = ((grow >> 7) + 1) << 7;
    unsigned short* row = S + (size_t)r * SEQ;
    const int t = threadIdx.x, lane = t & 63, w = t >> 6;

    float v[4][8];
    float mx = -1e30f;
    #pragma unroll
    for (int i = 0; i < 4; ++i) {
        int c0 = (i * 256 + t) * 8;
        if (c0 < Kcap) {
            short8 s8 = *(const short8*)(row + c0);
            #pragma unroll
            for (int j = 0; j < 8; ++j) {
                float f = bf2f((unsigned short)s8[j]);
                v[i][j] = (c0 + j <= grow) ? f : -1e30f;
                mx = fmaxf(mx, v[i][j]);
            }
        } else {
            #pragma unroll
            for (int j = 0; j < 8; ++j) v[i][j] = -1e30f;
        }
    }
    #pragma unroll
    for (int off = 32; off >= 1; off >>= 1)
        mx = fmaxf(mx, __shfl_xor(mx, off, 64));
    if (lane == 0) red[w] = mx;
    __syncthreads();
    mx = fmaxf(fmaxf(red[0], red[1]), fmaxf(red[2], red[3]));
    __syncthreads();

    float sum = 0.f;
    #pragma unroll
    for (int i = 0; i < 4; ++i)
        #pragma unroll
        for (int j = 0; j < 8; ++j) {
            float p = (v[i][j] > -1e29f) ? __expf(v[i][j] - mx) : 0.f;
            v[i][j] = p;
            sum += p;
        }
    #pragma unroll
    for (int off = 32; off >= 1; off >>= 1)
        sum += __shfl_xor(sum, off, 64);
    if (lane == 0) red[w] = sum;
    __syncthreads();
    sum = red[0] + red[1] + red[2] + red[3];
    const float inv = 1.0f / sum;

    #pragma unroll
    for (int i = 0; i < 4; ++i) {
        int c0 = (i * 256 + t) * 8;
        if (c0 < Kcap) {
            short8 o;
            #pragma unroll
            for (int j = 0; j < 8; ++j) o[j] = (short)f2bf(v[i][j] * inv);
            *(short8*)(row + c0) = o;
        }
    }
}

// ---------------------------------------------------------------------------
__global__ __launch_bounds__(256)
void cvt_bf16(const float* __restrict__ X, unsigned short* __restrict__ Y)
{
    int i = (blockIdx.x * 256 + threadIdx.x) * 8;
    f32x4 v0 = *(const f32x4*)(X + i);
    f32x4 v1 = *(const f32x4*)(X + i + 4);
    short8 o = { (short)f2bf(v0[0]), (short)f2bf(v0[1]),
                 (short)f2bf(v0[2]), (short)f2bf(v0[3]),
                 (short)f2bf(v1[0]), (short)f2bf(v1[1]),
                 (short)f2bf(v1[2]), (short)f2bf(v1[3]) };
    *(short8*)(Y + i) = o;
}

// ---------------------------------------------------------------------------
__global__ __launch_bounds__(256)
void twT(const float* __restrict__ W, unsigned short* __restrict__ WT)
{
    __shared__ float tile[64][65];
    const int bx = blockIdx.x * 64, by = blockIdx.y * 64;
    const int t = threadIdx.x, rr = t >> 4, c4 = (t & 15) * 4;
    #pragma unroll
    for (int i = 0; i < 4; ++i) {
        int r = rr + i * 16;
        f32x4 v = *(const f32x4*)(W + (size_t)(by + r) * DIM + bx + c4);
        tile[r][c4 + 0] = v[0]; tile[r][c4 + 1] = v[1];
        tile[r][c4 + 2] = v[2]; tile[r][c4 + 3] = v[3];
    }
    __syncthreads();
    #pragma unroll
    for (int i = 0; i < 4; ++i) {
        int r = rr + i * 16;                           // WT row = bx + r
        us4 o = { f2bf(tile[c4 + 0][r]), f2bf(tile[c4 + 1][r]),
                  f2bf(tile[c4 + 2][r]), f2bf(tile[c4 + 3][r]) };
        *(us4*)(WT + (size_t)(bx + r) * DIM + by + c4) = o;
    }
}

// ---------------------------------------------------------------------------
extern "C" void kernel_launch(void* const* d_in, const int* in_sizes, int n_in,
                              void* d_out, int out_size, void* d_ws, size_t ws_size,
                              hipStream_t stream)
{
    const float* x   = (const float*)d_in[0];
    const float* wq  = (const float*)d_in[1];
    const float* wk  = (const float*)d_in[2];
    const float* wv1 = (const float*)d_in[3];
    const float* wv2 = (const float*)d_in[4];

    // ws: Q/H bf16 [S,D] | K bf16 [S,D] | V^T bf16 [D,S] | split-K partials
    const size_t BUF = (size_t)SEQ * DIM * sizeof(unsigned short);  // 16 MiB
    unsigned short* qbuf  = (unsigned short*)d_ws;
    unsigned short* kbuf  = qbuf + (size_t)SEQ * DIM;
    unsigned short* vtbuf = kbuf + (size_t)SEQ * DIM;
    float* part = (float*)((char*)d_ws + 3 * BUF);
    const size_t PSZ = (size_t)2048 * 1024 * sizeof(float);         // 8 MiB
    int nsplit = 0;
    if (ws_size >= 3 * BUF + 2 * PSZ) {
        size_t ns = (ws_size - 3 * BUF) / PSZ;
        nsplit = (int)(ns < 4 ? ns : 4);
    }

    // d_out staging: xb + wT's during projections, then S bands.
    unsigned short* xb    = (unsigned short*)d_out;
    unsigned short* wqT   = xb + (size_t)SEQ * DIM;
    unsigned short* wkT   = wqT + DIM * DIM;
    unsigned short* wv1T  = wkT + DIM * DIM;
    unsigned short* Sband = (unsigned short*)d_out;

    dim3 tg(16, 16);
    cvt_bf16<<<SEQ * DIM / 2048, 256, 0, stream>>>(x, xb);
    twT<<<tg, 256, 0, stream>>>(wq,  wqT);
    twT<<<tg, 256, 0, stream>>>(wk,  wkT);
    twT<<<tg, 256, 0, stream>>>(wv1, wv1T);

    dim3 gproj(DIM / 128, SEQ / 128);
    gemm_bt<0,false,false,false,false><<<gproj, 256, 0, stream>>>(
        xb, wqT,  qbuf,  SEQ, DIM, DIM, 1.0f, 0, 0);
    gemm_bt<0,false,false,false,false><<<gproj, 256, 0, stream>>>(
        xb, wkT,  kbuf,  SEQ, DIM, DIM, 1.0f, 0, 0);
    gemm_bt<1,false,false,false,false><<<gproj, 256, 0, stream>>>(
        xb, wv1T, vtbuf, SEQ, DIM, DIM, 1.0f, 0, 0);

    constexpr int BAND = 2048;
    for (int b = 0; b < 4; ++b) {
        const int rb = b * BAND;
        const int ncol = (rb + BAND) / 128;        // prune all-masked columns
        dim3 gq(ncol, BAND / 128);
        gemm_bt<0,true,false,false,false><<<gq, 256, 0, stream>>>(
            qbuf + (size_t)rb * DIM, kbuf, Sband, BAND, SEQ, DIM, 0.03125f, rb, 0);
        if (b == 3)  // K no longer needed: stage wv2^T into kbuf
            twT<<<tg, 256, 0, stream>>>(wv2, kbuf);
        softmax_rows<<<BAND, 256, 0, stream>>>(Sband, rb);
        if (nsplit >= 2) {
            const int CH = (((rb + BAND) / nsplit + 63) / 64) * 64;
            dim3 gpv(DIM / 128, BAND / 128, nsplit);
            gemm_bt<3,false,true,false,true><<<gpv, 256, 0, stream>>>(
                Sband, vtbuf, part, BAND, DIM, SEQ, 1.0f, rb, CH);
            reduce_silu<<<BAND * DIM / 2048, 256, 0, stream>>>(
                part, qbuf + (size_t)rb * DIM, nsplit, CH, rb);
        } else {
            dim3 gpv(DIM / 128, BAND / 128);
            gemm_bt<0,false,true,true,false><<<gpv, 256, 0, stream>>>(
                Sband, vtbuf, qbuf + (size_t)rb * DIM, BAND, DIM, SEQ, 1.0f, rb, 0);
        }
    }

    gemm_bt<2,false,false,false,false><<<gproj, 256, 0, stream>>>(
        qbuf, kbuf, d_out, SEQ, DIM, DIM, 1.0f, 0, 0);
}

// Round 10
// 406.829 us; speedup vs baseline: 5.9246x; 1.0366x over previous
//
#include <hip/hip_runtime.h>
#include <hip/hip_bf16.h>
#include <cstdint>
#include <cstddef>

constexpr int SEQ = 8192;
constexpr int DIM = 1024;

typedef __attribute__((ext_vector_type(8))) short short8;   // bf16x8 MFMA frag
typedef __attribute__((ext_vector_type(4))) float f32x4;    // fp32x4 acc frag
typedef __attribute__((ext_vector_type(4))) unsigned short us4;

#define MFMA_BF16 __builtin_amdgcn_mfma_f32_16x16x32_bf16

static __device__ __forceinline__ unsigned short f2bf(float f) {
    uint32_t u = __builtin_bit_cast(uint32_t, f);
    u += 0x7FFFu + ((u >> 16) & 1u);      // round-to-nearest-even
    return (unsigned short)(u >> 16);
}
static __device__ __forceinline__ float bf2f(unsigned short h) {
    uint32_t u = ((uint32_t)h) << 16;
    return __builtin_bit_cast(float, u);
}
static __device__ __forceinline__ int r64(int x) {          // round to mult of 64
    return ((x + 32) >> 6) << 6;
}

#define GLOAD16(gp, lp) __builtin_amdgcn_global_load_lds(                      \
    (const __attribute__((address_space(1))) void*)(gp),                       \
    (__attribute__((address_space(3))) void*)(lp), 16, 0, 0)

// ---------------------------------------------------------------------------
// GEMM: C[M,N] = A[M,K] @ Bt[N,K]^T   (A, Bt bf16 row-major; Bt is B^T)
// BM=128, BK=64, BN=128. 256 threads = 4 waves (2x2 wave grid).
// Counted pipeline: raw s_barrier + one vmcnt(0) AFTER the MFMA phase so
// prefetch gloads stay in flight across compute. setprio around MFMA (T5).
// XOR slot-swizzle on global source + ds_read address (0 bank conflicts).
// Bijective chunked XCD swizzle (T1/m204) so consecutive tiles that share
// the A-panel land on one XCD's L2.
// OM: 0=bf16 C[M,N]; 1=bf16 C[N,M]; 2=fp32 C[M,N]; 3=fp32 partial (split-K).
// SPLITK: even per-row split — k range [r64(z*Keff/NS), r64((z+1)*Keff/NS)).
// ---------------------------------------------------------------------------
template<int OM, bool CAUSAL, bool KCAP, bool SILU, bool SPLITK>
__global__ __launch_bounds__(256, 2)
void gemm_bt(const unsigned short* __restrict__ A,
             const unsigned short* __restrict__ Bt,
             void* __restrict__ Cp,
             int M, int N, int K, float scale, int rowBase, int NS)
{
    constexpr int BM = 128, BK = 64, BN = 128;
    constexpr int NF = BN / 32;           // 4 b-frags per wave
    __shared__ __align__(16) unsigned short As[2][BM * BK];
    __shared__ __align__(16) unsigned short Bs[2][BN * BK];

    const int t = threadIdx.x, lane = t & 63, w = t >> 6;
    const int wr = w >> 1, wc = w & 1;
    const int ln15 = lane & 15, hi = lane >> 4;

    // ---- chunked-bijective XCD swizzle over the flattened grid
    const int gx = gridDim.x, gy = gridDim.y;
    const int nwg = gx * gy * gridDim.z;
    const int orig = blockIdx.x + gx * (blockIdx.y + gy * blockIdx.z);
    const int q = nwg >> 3, r8 = nwg & 7;
    const int xcd = orig & 7, idx = orig >> 3;
    const int wg = (xcd < r8 ? xcd * (q + 1)
                             : r8 * (q + 1) + (xcd - r8) * q) + idx;
    const int bxi = wg % gx, tmpw = wg / gx;
    const int byi = tmpw % gy, bzi = tmpw / gy;

    const int bm = byi * BM, bn = bxi * BN;

    if (CAUSAL && bn > rowBase + bm + (BM - 1)) return;   // fully-masked tile
    int Keff = K;
    if (KCAP) { int kc = rowBase + bm + BM; Keff = kc < K ? kc : K; }
    int kbeg = 0, kend = Keff;
    if (SPLITK) {
        kbeg = r64(bzi * Keff / NS);
        int ke = r64((bzi + 1) * Keff / NS);
        kend = ke < Keff ? ke : Keff;
        if (kbeg >= kend) return;          // empty slice (small Keff rows)
    }

#define STAGE_TILES(buf, k0) do {                                              \
        _Pragma("unroll")                                                      \
        for (int i = 0; i < 4; ++i) {                                          \
            int c = t + 256 * i;                                               \
            int r = c >> 3, qq = (c & 7) ^ (r & 7);                            \
            GLOAD16(A + (size_t)(bm + r) * K + (k0) + qq * 8,                  \
                    &As[buf][c * 8]);                                          \
        }                                                                      \
        _Pragma("unroll")                                                      \
        for (int i = 0; i < 4; ++i) {                                          \
            int c = t + 256 * i;                                               \
            int r = c >> 3, qq = (c & 7) ^ (r & 7);                            \
            GLOAD16(Bt + (size_t)(bn + r) * K + (k0) + qq * 8,                 \
                    &Bs[buf][c * 8]);                                          \
        }                                                                      \
    } while (0)

    f32x4 acc[4][NF] = {};

    STAGE_TILES(0, kbeg);
    asm volatile("s_waitcnt vmcnt(0)" ::: "memory");
    __builtin_amdgcn_s_barrier();
    int cur = 0;
    for (int k0 = kbeg; k0 < kend; k0 += BK) {
        if (k0 + BK < kend) STAGE_TILES(cur ^ 1, k0 + BK);   // prefetch next

        #pragma unroll
        for (int kk = 0; kk < 2; ++kk) {
            short8 a[4], b[NF];
            #pragma unroll
            for (int m = 0; m < 4; ++m) {
                int r = wr * 64 + m * 16 + ln15;
                int s = (kk * 4 + hi) ^ (r & 7);          // swizzled read
                a[m] = *(const short8*)(&As[cur][r * 64 + s * 8]);
            }
            #pragma unroll
            for (int n = 0; n < NF; ++n) {
                int r = wc * 64 + n * 16 + ln15;
                int s = (kk * 4 + hi) ^ (r & 7);
                b[n] = *(const short8*)(&Bs[cur][r * 64 + s * 8]);
            }
            __builtin_amdgcn_s_setprio(1);
            #pragma unroll
            for (int m = 0; m < 4; ++m)
                #pragma unroll
                for (int n = 0; n < NF; ++n)
                    acc[m][n] = MFMA_BF16(a[m], b[n], acc[m][n], 0, 0, 0);
            __builtin_amdgcn_s_setprio(0);
        }
        // own prefetch landed; all waves done reading buf[cur] after barrier
        asm volatile("s_waitcnt vmcnt(0)" ::: "memory");
        __builtin_amdgcn_s_barrier();
        cur ^= 1;
    }
#undef STAGE_TILES

    // ---- epilogue: C/D layout col = lane&15, row = (lane>>4)*4 + j
    float* Pz = (OM == 3)
        ? (float*)Cp + (size_t)bzi * M * N : nullptr;
    #pragma unroll
    for (int m = 0; m < 4; ++m)
        #pragma unroll
        for (int n = 0; n < NF; ++n)
            #pragma unroll
            for (int j = 0; j < 4; ++j) {
                int row = bm + wr * 64 + m * 16 + hi * 4 + j;
                int col = bn + wc * 64 + n * 16 + ln15;
                float v = acc[m][n][j] * scale;
                if (SILU) v = v / (1.0f + __expf(-v));
                if (OM == 0)
                    ((unsigned short*)Cp)[(size_t)row * N + col] = f2bf(v);
                else if (OM == 1)
                    ((unsigned short*)Cp)[(size_t)col * M + row] = f2bf(v);
                else if (OM == 2)
                    ((float*)Cp)[(size_t)row * N + col] = v;
                else
                    Pz[(size_t)row * N + col] = v;
            }
}

// ---------------------------------------------------------------------------
// Split-K reduction: sum non-empty fp32 partial slices (same even per-row
// boundaries as the PV kernel), SiLU, bf16 -> out (band rows).
// ---------------------------------------------------------------------------
__global__ __launch_bounds__(256)
void reduce_silu(const float* __restrict__ part, unsigned short* __restrict__ out,
                 int ns, int rowBase)
{
    const size_t idx = ((size_t)blockIdx.x * 256 + threadIdx.x) * 8;
    const int r = (int)(idx >> 10);                 // DIM = 1024
    int keb = rowBase + ((r >> 7) << 7) + 128;      // Keff of r's PV block-row
    if (keb > SEQ) keb = SEQ;

    f32x4 s0 = {}, s1 = {};
    for (int z = 0; z < ns; ++z) {
        int b0 = r64(z * keb / ns);
        int b1 = r64((z + 1) * keb / ns);
        if (b1 > keb) b1 = keb;
        if (b1 > b0) {
            const float* p = part + (size_t)z * (2048 * 1024) + idx;
            s0 += *(const f32x4*)p;
            s1 += *(const f32x4*)(p + 4);
        }
    }
    short8 o;
    #pragma unroll
    for (int j = 0; j < 4; ++j) {
        float v = s0[j];
        o[j] = (short)f2bf(v / (1.0f + __expf(-v)));
    }
    #pragma unroll
    for (int j = 0; j < 4; ++j) {
        float v = s1[j];
        o[4 + j] = (short)f2bf(v / (1.0f + __expf(-v)));
    }
    *(short8*)(out + idx) = o;
}

// ---------------------------------------------------------------------------
// Row softmax over a 2048-row band of S (bf16 [2048][8192]), in place.
// Valid cols [0, grow], zero-fill to the 128 boundary Kcap.
// ---------------------------------------------------------------------------
__global__ __launch_bounds__(256)
void softmax_rows(unsigned short* __restrict__ S, int rowBase)
{
    __shared__ float red[4];
    const int r = blockIdx.x;
    const int grow = rowBase + r;
    const int Kcap = ((grow >> 7) + 1) << 7;
    unsigned short* row = S + (size_t)r * SEQ;
    const int t = threadIdx.x, lane = t & 63, w = t >> 6;

    float v[4][8];
    float mx = -1e30f;
    #pragma unroll
    for (int i = 0; i < 4; ++i) {
        int c0 = (i * 256 + t) * 8;
        if (c0 < Kcap) {
            short8 s8 = *(const short8*)(row + c0);
            #pragma unroll
            for (int j = 0; j < 8; ++j) {
                float f = bf2f((unsigned short)s8[j]);
                v[i][j] = (c0 + j <= grow) ? f : -1e30f;
                mx = fmaxf(mx, v[i][j]);
            }
        } else {
            #pragma unroll
            for (int j = 0; j < 8; ++j) v[i][j] = -1e30f;
        }
    }
    #pragma unroll
    for (int off = 32; off >= 1; off >>= 1)
        mx = fmaxf(mx, __shfl_xor(mx, off, 64));
    if (lane == 0) red[w] = mx;
    __syncthreads();
    mx = fmaxf(fmaxf(red[0], red[1]), fmaxf(red[2], red[3]));
    __syncthreads();

    float sum = 0.f;
    #pragma unroll
    for (int i = 0; i < 4; ++i)
        #pragma unroll
        for (int j = 0; j < 8; ++j) {
            float p = (v[i][j] > -1e29f) ? __expf(v[i][j] - mx) : 0.f;
            v[i][j] = p;
            sum += p;
        }
    #pragma unroll
    for (int off = 32; off >= 1; off >>= 1)
        sum += __shfl_xor(sum, off, 64);
    if (lane == 0) red[w] = sum;
    __syncthreads();
    sum = red[0] + red[1] + red[2] + red[3];
    const float inv = 1.0f / sum;

    #pragma unroll
    for (int i = 0; i < 4; ++i) {
        int c0 = (i * 256 + t) * 8;
        if (c0 < Kcap) {
            short8 o;
            #pragma unroll
            for (int j = 0; j < 8; ++j) o[j] = (short)f2bf(v[i][j] * inv);
            *(short8*)(row + c0) = o;
        }
    }
}

// ---------------------------------------------------------------------------
__global__ __launch_bounds__(256)
void cvt_bf16(const float* __restrict__ X, unsigned short* __restrict__ Y)
{
    int i = (blockIdx.x * 256 + threadIdx.x) * 8;
    f32x4 v0 = *(const f32x4*)(X + i);
    f32x4 v1 = *(const f32x4*)(X + i + 4);
    short8 o = { (short)f2bf(v0[0]), (short)f2bf(v0[1]),
                 (short)f2bf(v0[2]), (short)f2bf(v0[3]),
                 (short)f2bf(v1[0]), (short)f2bf(v1[1]),
                 (short)f2bf(v1[2]), (short)f2bf(v1[3]) };
    *(short8*)(Y + i) = o;
}

// ---------------------------------------------------------------------------
__global__ __launch_bounds__(256)
void twT(const float* __restrict__ W, unsigned short* __restrict__ WT)
{
    __shared__ float tile[64][65];
    const int bx = blockIdx.x * 64, by = blockIdx.y * 64;
    const int t = threadIdx.x, rr = t >> 4, c4 = (t & 15) * 4;
    #pragma unroll
    for (int i = 0; i < 4; ++i) {
        int r = rr + i * 16;
        f32x4 v = *(const f32x4*)(W + (size_t)(by + r) * DIM + bx + c4);
        tile[r][c4 + 0] = v[0]; tile[r][c4 + 1] = v[1];
        tile[r][c4 + 2] = v[2]; tile[r][c4 + 3] = v[3];
    }
    __syncthreads();
    #pragma unroll
    for (int i = 0; i < 4; ++i) {
        int r = rr + i * 16;                           // WT row = bx + r
        us4 o = { f2bf(tile[c4 + 0][r]), f2bf(tile[c4 + 1][r]),
                  f2bf(tile[c4 + 2][r]), f2bf(tile[c4 + 3][r]) };
        *(us4*)(WT + (size_t)(bx + r) * DIM + by + c4) = o;
    }
}

// ---------------------------------------------------------------------------
extern "C" void kernel_launch(void* const* d_in, const int* in_sizes, int n_in,
                              void* d_out, int out_size, void* d_ws, size_t ws_size,
                              hipStream_t stream)
{
    const float* x   = (const float*)d_in[0];
    const float* wq  = (const float*)d_in[1];
    const float* wk  = (const float*)d_in[2];
    const float* wv1 = (const float*)d_in[3];
    const float* wv2 = (const float*)d_in[4];

    // ws: Q/H bf16 [S,D] | K bf16 [S,D] | V^T bf16 [D,S] | split-K partials
    const size_t BUF = (size_t)SEQ * DIM * sizeof(unsigned short);  // 16 MiB
    unsigned short* qbuf  = (unsigned short*)d_ws;
    unsigned short* kbuf  = qbuf + (size_t)SEQ * DIM;
    unsigned short* vtbuf = kbuf + (size_t)SEQ * DIM;
    float* part = (float*)((char*)d_ws + 3 * BUF);
    const size_t PSZ = (size_t)2048 * 1024 * sizeof(float);         // 8 MiB
    int nsplit = 0;
    if (ws_size >= 3 * BUF + 2 * PSZ) {
        size_t ns = (ws_size - 3 * BUF) / PSZ;
        nsplit = (int)(ns < 4 ? ns : 4);
    }

    // d_out staging: xb + wT's during projections, then S bands.
    unsigned short* xb    = (unsigned short*)d_out;
    unsigned short* wqT   = xb + (size_t)SEQ * DIM;
    unsigned short* wkT   = wqT + DIM * DIM;
    unsigned short* wv1T  = wkT + DIM * DIM;
    unsigned short* Sband = (unsigned short*)d_out;

    dim3 tg(16, 16);
    cvt_bf16<<<SEQ * DIM / 2048, 256, 0, stream>>>(x, xb);
    twT<<<tg, 256, 0, stream>>>(wq,  wqT);
    twT<<<tg, 256, 0, stream>>>(wk,  wkT);
    twT<<<tg, 256, 0, stream>>>(wv1, wv1T);

    dim3 gproj(DIM / 128, SEQ / 128);
    gemm_bt<0,false,false,false,false><<<gproj, 256, 0, stream>>>(
        xb, wqT,  qbuf,  SEQ, DIM, DIM, 1.0f, 0, 0);
    gemm_bt<0,false,false,false,false><<<gproj, 256, 0, stream>>>(
        xb, wkT,  kbuf,  SEQ, DIM, DIM, 1.0f, 0, 0);
    gemm_bt<1,false,false,false,false><<<gproj, 256, 0, stream>>>(
        xb, wv1T, vtbuf, SEQ, DIM, DIM, 1.0f, 0, 0);

    constexpr int BAND = 2048;
    for (int b = 0; b < 4; ++b) {
        const int rb = b * BAND;
        const int ncol = (rb + BAND) / 128;        // prune all-masked columns
        dim3 gq(ncol, BAND / 128);
        gemm_bt<0,true,false,false,false><<<gq, 256, 0, stream>>>(
            qbuf + (size_t)rb * DIM, kbuf, Sband, BAND, SEQ, DIM, 0.03125f, rb, 0);
        if (b == 3)  // K no longer needed: stage wv2^T into kbuf
            twT<<<tg, 256, 0, stream>>>(wv2, kbuf);
        softmax_rows<<<BAND, 256, 0, stream>>>(Sband, rb);
        if (nsplit >= 2) {
            dim3 gpv(DIM / 128, BAND / 128, nsplit);
            gemm_bt<3,false,true,false,true><<<gpv, 256, 0, stream>>>(
                Sband, vtbuf, part, BAND, DIM, SEQ, 1.0f, rb, nsplit);
            reduce_silu<<<BAND * DIM / 2048, 256, 0, stream>>>(
                part, qbuf + (size_t)rb * DIM, nsplit, rb);
        } else {
            dim3 gpv(DIM / 128, BAND / 128);
            gemm_bt<0,false,true,true,false><<<gpv, 256, 0, stream>>>(
                Sband, vtbuf, qbuf + (size_t)rb * DIM, BAND, DIM, SEQ, 1.0f, rb, 0);
        }
    }

    gemm_bt<2,false,false,false,false><<<gproj, 256, 0, stream>>>(
        qbuf, kbuf, d_out, SEQ, DIM, DIM, 1.0f, 0, 0);
}

// Round 11
// 406.165 us; speedup vs baseline: 5.9343x; 1.0016x over previous
//
#include <hip/hip_runtime.h>
#include <hip/hip_bf16.h>
#include <cstdint>
#include <cstddef>

constexpr int SEQ = 8192;
constexpr int DIM = 1024;

typedef __attribute__((ext_vector_type(8))) short short8;   // bf16x8 MFMA frag
typedef __attribute__((ext_vector_type(4))) float f32x4;    // fp32x4 acc frag
typedef __attribute__((ext_vector_type(4))) unsigned short us4;

#define MFMA_BF16 __builtin_amdgcn_mfma_f32_16x16x32_bf16

static __device__ __forceinline__ unsigned short f2bf(float f) {
    uint32_t u = __builtin_bit_cast(uint32_t, f);
    u += 0x7FFFu + ((u >> 16) & 1u);      // round-to-nearest-even
    return (unsigned short)(u >> 16);
}
static __device__ __forceinline__ float bf2f(unsigned short h) {
    uint32_t u = ((uint32_t)h) << 16;
    return __builtin_bit_cast(float, u);
}
static __device__ __forceinline__ int r64(int x) {          // round to mult of 64
    return ((x + 32) >> 6) << 6;
}

#define GLOAD16(gp, lp) __builtin_amdgcn_global_load_lds(                      \
    (const __attribute__((address_space(1))) void*)(gp),                       \
    (__attribute__((address_space(3))) void*)(lp), 16, 0, 0)

// ---------------------------------------------------------------------------
// GEMM: C[M,N] = A[M,K] @ Bt[N,K]^T   (A, Bt bf16 row-major; Bt is B^T)
// BM=128, BK=64, BN=128. 256 threads = 4 waves (2x2 wave grid).
// T4 counted pipeline: per K-step issue next tile's 8 global_load_lds, then
// s_waitcnt vmcnt(8) (wait for CURRENT tile only; next stays in flight under
// the MFMA phase), s_barrier, ds_read+MFMA, s_barrier. Last step drains 0.
// setprio around MFMA (T5). XOR slot-swizzle on global source + ds_read
// address (0 bank conflicts). Bijective chunked XCD swizzle with Y-FASTEST
// flatten: an XCD chunk = many bm x few bn -> A-band + B-panels L2-resident
// (fixes the 5.6x QK^T over-fetch).
// OM: 0=bf16 C[M,N]; 1=bf16 C[N,M]; 2=fp32 C[M,N]; 3=fp32 partial (split-K).
// SPLITK: even per-row split — k range [r64(z*Keff/NS), r64((z+1)*Keff/NS)).
// ---------------------------------------------------------------------------
template<int OM, bool CAUSAL, bool KCAP, bool SILU, bool SPLITK>
__global__ __launch_bounds__(256, 2)
void gemm_bt(const unsigned short* __restrict__ A,
             const unsigned short* __restrict__ Bt,
             void* __restrict__ Cp,
             int M, int N, int K, float scale, int rowBase, int NS)
{
    constexpr int BM = 128, BK = 64, BN = 128;
    constexpr int NF = BN / 32;           // 4 b-frags per wave
    __shared__ __align__(16) unsigned short As[2][BM * BK];
    __shared__ __align__(16) unsigned short Bs[2][BN * BK];

    const int t = threadIdx.x;
    const int lane = t & 63, w = t >> 6;
    const int wr = w >> 1, wc = w & 1;
    const int ln15 = lane & 15, hi = lane >> 4;

    // ---- chunked-bijective XCD swizzle, Y-FASTEST flatten (B-panel locality)
    const int gx = gridDim.x, gy = gridDim.y;
    const int nwg = gx * gy * gridDim.z;
    const int orig = blockIdx.y + gy * (blockIdx.x + gx * blockIdx.z);
    const int q = nwg >> 3, r8 = nwg & 7;
    const int xcd = orig & 7, idx = orig >> 3;
    const int wg = (xcd < r8 ? xcd * (q + 1)
                             : r8 * (q + 1) + (xcd - r8) * q) + idx;
    const int byi = wg % gy, tmpw = wg / gy;
    const int bxi = tmpw % gx, bzi = tmpw / gx;

    const int bm = byi * BM, bn = bxi * BN;

    if (CAUSAL && bn > rowBase + bm + (BM - 1)) return;   // fully-masked tile
    int Keff = K;
    if (KCAP) { int kc = rowBase + bm + BM; Keff = kc < K ? kc : K; }
    int kbeg = 0, kend = Keff;
    if (SPLITK) {
        kbeg = r64(bzi * Keff / NS);
        int ke = r64((bzi + 1) * Keff / NS);
        kend = ke < Keff ? ke : Keff;
        if (kbeg >= kend) return;          // empty slice (small Keff rows)
    }

#define STAGE_TILES(buf, k0) do {                                              \
        _Pragma("unroll")                                                      \
        for (int i = 0; i < 4; ++i) {                                          \
            int c = t + 256 * i;                                               \
            int r = c >> 3, qq = (c & 7) ^ (r & 7);                            \
            GLOAD16(A + (size_t)(bm + r) * K + (k0) + qq * 8,                  \
                    &As[buf][c * 8]);                                          \
        }                                                                      \
        _Pragma("unroll")                                                      \
        for (int i = 0; i < 4; ++i) {                                          \
            int c = t + 256 * i;                                               \
            int r = c >> 3, qq = (c & 7) ^ (r & 7);                            \
            GLOAD16(Bt + (size_t)(bn + r) * K + (k0) + qq * 8,                 \
                    &Bs[buf][c * 8]);                                          \
        }                                                                      \
    } while (0)

    f32x4 acc[4][NF] = {};

    STAGE_TILES(0, kbeg);                  // prologue: 8 loads in flight
    int cur = 0;
    for (int k0 = kbeg; k0 < kend; k0 += BK) {
        if (k0 + BK < kend) {
            STAGE_TILES(cur ^ 1, k0 + BK);              // +8 loads (16 total)
            asm volatile("s_waitcnt vmcnt(8)" ::: "memory");  // cur's 8 landed
        } else {
            asm volatile("s_waitcnt vmcnt(0)" ::: "memory");  // tail: drain
        }
        __builtin_amdgcn_s_barrier();      // all waves' cur tile complete
        asm volatile("" ::: "memory");     // keep ds_reads below the barrier

        #pragma unroll
        for (int kk = 0; kk < 2; ++kk) {
            short8 a[4], b[NF];
            #pragma unroll
            for (int m = 0; m < 4; ++m) {
                int r = wr * 64 + m * 16 + ln15;
                int s = (kk * 4 + hi) ^ (r & 7);          // swizzled read
                a[m] = *(const short8*)(&As[cur][r * 64 + s * 8]);
            }
            #pragma unroll
            for (int n = 0; n < NF; ++n) {
                int r = wc * 64 + n * 16 + ln15;
                int s = (kk * 4 + hi) ^ (r & 7);
                b[n] = *(const short8*)(&Bs[cur][r * 64 + s * 8]);
            }
            __builtin_amdgcn_s_setprio(1);
            #pragma unroll
            for (int m = 0; m < 4; ++m)
                #pragma unroll
                for (int n = 0; n < NF; ++n)
                    acc[m][n] = MFMA_BF16(a[m], b[n], acc[m][n], 0, 0, 0);
            __builtin_amdgcn_s_setprio(0);
        }
        asm volatile("" ::: "memory");
        __builtin_amdgcn_s_barrier();      // all waves done reading buf[cur]
        cur ^= 1;
    }
#undef STAGE_TILES

    // ---- epilogue: C/D layout col = lane&15, row = (lane>>4)*4 + j
    float* Pz = (OM == 3)
        ? (float*)Cp + (size_t)bzi * M * N : nullptr;
    #pragma unroll
    for (int m = 0; m < 4; ++m)
        #pragma unroll
        for (int n = 0; n < NF; ++n)
            #pragma unroll
            for (int j = 0; j < 4; ++j) {
                int row = bm + wr * 64 + m * 16 + hi * 4 + j;
                int col = bn + wc * 64 + n * 16 + ln15;
                float v = acc[m][n][j] * scale;
                if (SILU) v = v / (1.0f + __expf(-v));
                if (OM == 0)
                    ((unsigned short*)Cp)[(size_t)row * N + col] = f2bf(v);
                else if (OM == 1)
                    ((unsigned short*)Cp)[(size_t)col * M + row] = f2bf(v);
                else if (OM == 2)
                    ((float*)Cp)[(size_t)row * N + col] = v;
                else
                    Pz[(size_t)row * N + col] = v;
            }
}

// ---------------------------------------------------------------------------
// Split-K reduction: sum non-empty fp32 partial slices (same even per-row
// boundaries as the PV kernel), SiLU, bf16 -> out (band rows).
// ---------------------------------------------------------------------------
__global__ __launch_bounds__(256)
void reduce_silu(const float* __restrict__ part, unsigned short* __restrict__ out,
                 int ns, int rowBase)
{
    const size_t idx = ((size_t)blockIdx.x * 256 + threadIdx.x) * 8;
    const int r = (int)(idx >> 10);                 // DIM = 1024
    int keb = rowBase + ((r >> 7) << 7) + 128;      // Keff of r's PV block-row
    if (keb > SEQ) keb = SEQ;

    f32x4 s0 = {}, s1 = {};
    for (int z = 0; z < ns; ++z) {
        int b0 = r64(z * keb / ns);
        int b1 = r64((z + 1) * keb / ns);
        if (b1 > keb) b1 = keb;
        if (b1 > b0) {
            const float* p = part + (size_t)z * (2048 * 1024) + idx;
            s0 += *(const f32x4*)p;
            s1 += *(const f32x4*)(p + 4);
        }
    }
    short8 o;
    #pragma unroll
    for (int j = 0; j < 4; ++j) {
        float v = s0[j];
        o[j] = (short)f2bf(v / (1.0f + __expf(-v)));
    }
    #pragma unroll
    for (int j = 0; j < 4; ++j) {
        float v = s1[j];
        o[4 + j] = (short)f2bf(v / (1.0f + __expf(-v)));
    }
    *(short8*)(out + idx) = o;
}

// ---------------------------------------------------------------------------
// Row softmax over a 2048-row band of S (bf16 [2048][8192]), in place.
// Valid cols [0, grow], zero-fill to the 128 boundary Kcap.
// ---------------------------------------------------------------------------
__global__ __launch_bounds__(256)
void softmax_rows(unsigned short* __restrict__ S, int rowBase)
{
    __shared__ float red[4];
    const int r = blockIdx.x;
    const int grow = rowBase + r;
    const int Kcap = ((grow >> 7) + 1) << 7;
    unsigned short* row = S + (size_t)r * SEQ;
    const int t = threadIdx.x, lane = t & 63, w = t >> 6;

    float v[4][8];
    float mx = -1e30f;
    #pragma unroll
    for (int i = 0; i < 4; ++i) {
        int c0 = (i * 256 + t) * 8;
        if (c0 < Kcap) {
            short8 s8 = *(const short8*)(row + c0);
            #pragma unroll
            for (int j = 0; j < 8; ++j) {
                float f = bf2f((unsigned short)s8[j]);
                v[i][j] = (c0 + j <= grow) ? f : -1e30f;
                mx = fmaxf(mx, v[i][j]);
            }
        } else {
            #pragma unroll
            for (int j = 0; j < 8; ++j) v[i][j] = -1e30f;
        }
    }
    #pragma unroll
    for (int off = 32; off >= 1; off >>= 1)
        mx = fmaxf(mx, __shfl_xor(mx, off, 64));
    if (lane == 0) red[w] = mx;
    __syncthreads();
    mx = fmaxf(fmaxf(red[0], red[1]), fmaxf(red[2], red[3]));
    __syncthreads();

    float sum = 0.f;
    #pragma unroll
    for (int i = 0; i < 4; ++i)
        #pragma unroll
        for (int j = 0; j < 8; ++j) {
            float p = (v[i][j] > -1e29f) ? __expf(v[i][j] - mx) : 0.f;
            v[i][j] = p;
            sum += p;
        }
    #pragma unroll
    for (int off = 32; off >= 1; off >>= 1)
        sum += __shfl_xor(sum, off, 64);
    if (lane == 0) red[w] = sum;
    __syncthreads();
    sum = red[0] + red[1] + red[2] + red[3];
    const float inv = 1.0f / sum;

    #pragma unroll
    for (int i = 0; i < 4; ++i) {
        int c0 = (i * 256 + t) * 8;
        if (c0 < Kcap) {
            short8 o;
            #pragma unroll
            for (int j = 0; j < 8; ++j) o[j] = (short)f2bf(v[i][j] * inv);
            *(short8*)(row + c0) = o;
        }
    }
}

// ---------------------------------------------------------------------------
__global__ __launch_bounds__(256)
void cvt_bf16(const float* __restrict__ X, unsigned short* __restrict__ Y)
{
    int i = (blockIdx.x * 256 + threadIdx.x) * 8;
    f32x4 v0 = *(const f32x4*)(X + i);
    f32x4 v1 = *(const f32x4*)(X + i + 4);
    short8 o = { (short)f2bf(v0[0]), (short)f2bf(v0[1]),
                 (short)f2bf(v0[2]), (short)f2bf(v0[3]),
                 (short)f2bf(v1[0]), (short)f2bf(v1[1]),
                 (short)f2bf(v1[2]), (short)f2bf(v1[3]) };
    *(short8*)(Y + i) = o;
}

// ---------------------------------------------------------------------------
__global__ __launch_bounds__(256)
void twT(const float* __restrict__ W, unsigned short* __restrict__ WT)
{
    __shared__ float tile[64][65];
    const int bx = blockIdx.x * 64, by = blockIdx.y * 64;
    const int t = threadIdx.x, rr = t >> 4, c4 = (t & 15) * 4;
    #pragma unroll
    for (int i = 0; i < 4; ++i) {
        int r = rr + i * 16;
        f32x4 v = *(const f32x4*)(W + (size_t)(by + r) * DIM + bx + c4);
        tile[r][c4 + 0] = v[0]; tile[r][c4 + 1] = v[1];
        tile[r][c4 + 2] = v[2]; tile[r][c4 + 3] = v[3];
    }
    __syncthreads();
    #pragma unroll
    for (int i = 0; i < 4; ++i) {
        int r = rr + i * 16;                           // WT row = bx + r
        us4 o = { f2bf(tile[c4 + 0][r]), f2bf(tile[c4 + 1][r]),
                  f2bf(tile[c4 + 2][r]), f2bf(tile[c4 + 3][r]) };
        *(us4*)(WT + (size_t)(bx + r) * DIM + by + c4) = o;
    }
}

// ---------------------------------------------------------------------------
extern "C" void kernel_launch(void* const* d_in, const int* in_sizes, int n_in,
                              void* d_out, int out_size, void* d_ws, size_t ws_size,
                              hipStream_t stream)
{
    const float* x   = (const float*)d_in[0];
    const float* wq  = (const float*)d_in[1];
    const float* wk  = (const float*)d_in[2];
    const float* wv1 = (const float*)d_in[3];
    const float* wv2 = (const float*)d_in[4];

    // ws: Q/H bf16 [S,D] | K bf16 [S,D] | V^T bf16 [D,S] | split-K partials
    const size_t BUF = (size_t)SEQ * DIM * sizeof(unsigned short);  // 16 MiB
    unsigned short* qbuf  = (unsigned short*)d_ws;
    unsigned short* kbuf  = qbuf + (size_t)SEQ * DIM;
    unsigned short* vtbuf = kbuf + (size_t)SEQ * DIM;
    float* part = (float*)((char*)d_ws + 3 * BUF);
    const size_t PSZ = (size_t)2048 * 1024 * sizeof(float);         // 8 MiB
    int nsplit = 0;
    if (ws_size >= 3 * BUF + 2 * PSZ) {
        size_t ns = (ws_size - 3 * BUF) / PSZ;
        nsplit = (int)(ns < 4 ? ns : 4);
    }

    // d_out staging: xb + wT's during projections, then S bands.
    unsigned short* xb    = (unsigned short*)d_out;
    unsigned short* wqT   = xb + (size_t)SEQ * DIM;
    unsigned short* wkT   = wqT + DIM * DIM;
    unsigned short* wv1T  = wkT + DIM * DIM;
    unsigned short* Sband = (unsigned short*)d_out;

    dim3 tg(16, 16);
    cvt_bf16<<<SEQ * DIM / 2048, 256, 0, stream>>>(x, xb);
    twT<<<tg, 256, 0, stream>>>(wq,  wqT);
    twT<<<tg, 256, 0, stream>>>(wk,  wkT);
    twT<<<tg, 256, 0, stream>>>(wv1, wv1T);

    dim3 gproj(DIM / 128, SEQ / 128);
    gemm_bt<0,false,false,false,false><<<gproj, 256, 0, stream>>>(
        xb, wqT,  qbuf,  SEQ, DIM, DIM, 1.0f, 0, 0);
    gemm_bt<0,false,false,false,false><<<gproj, 256, 0, stream>>>(
        xb, wkT,  kbuf,  SEQ, DIM, DIM, 1.0f, 0, 0);
    gemm_bt<1,false,false,false,false><<<gproj, 256, 0, stream>>>(
        xb, wv1T, vtbuf, SEQ, DIM, DIM, 1.0f, 0, 0);

    constexpr int BAND = 2048;
    for (int b = 0; b < 4; ++b) {
        const int rb = b * BAND;
        const int ncol = (rb + BAND) / 128;        // prune all-masked columns
        dim3 gq(ncol, BAND / 128);
        gemm_bt<0,true,false,false,false><<<gq, 256, 0, stream>>>(
            qbuf + (size_t)rb * DIM, kbuf, Sband, BAND, SEQ, DIM, 0.03125f, rb, 0);
        if (b == 3)  // K no longer needed: stage wv2^T into kbuf
            twT<<<tg, 256, 0, stream>>>(wv2, kbuf);
        softmax_rows<<<BAND, 256, 0, stream>>>(Sband, rb);
        if (nsplit >= 2) {
            dim3 gpv(DIM / 128, BAND / 128, nsplit);
            gemm_bt<3,false,true,false,true><<<gpv, 256, 0, stream>>>(
                Sband, vtbuf, part, BAND, DIM, SEQ, 1.0f, rb, nsplit);
            reduce_silu<<<BAND * DIM / 2048, 256, 0, stream>>>(
                part, qbuf + (size_t)rb * DIM, nsplit, rb);
        } else {
            dim3 gpv(DIM / 128, BAND / 128);
            gemm_bt<0,false,true,true,false><<<gpv, 256, 0, stream>>>(
                Sband, vtbuf, qbuf + (size_t)rb * DIM, BAND, DIM, SEQ, 1.0f, rb, 0);
        }
    }

    gemm_bt<2,false,false,false,false><<<gproj, 256, 0, stream>>>(
        qbuf, kbuf, d_out, SEQ, DIM, DIM, 1.0f, 0, 0);
}

// Round 12
// 387.396 us; speedup vs baseline: 6.2218x; 1.0484x over previous
//
#include <hip/hip_runtime.h>
#include <hip/hip_bf16.h>
#include <cstdint>
#include <cstddef>

constexpr int SEQ = 8192;
constexpr int DIM = 1024;

typedef __attribute__((ext_vector_type(8))) short short8;   // bf16x8 MFMA frag
typedef __attribute__((ext_vector_type(4))) float f32x4;    // fp32x4 acc frag
typedef __attribute__((ext_vector_type(4))) unsigned short us4;

#define MFMA_BF16 __builtin_amdgcn_mfma_f32_16x16x32_bf16

static __device__ __forceinline__ unsigned short f2bf(float f) {
    uint32_t u = __builtin_bit_cast(uint32_t, f);
    u += 0x7FFFu + ((u >> 16) & 1u);      // round-to-nearest-even
    return (unsigned short)(u >> 16);
}
static __device__ __forceinline__ float bf2f(unsigned short h) {
    uint32_t u = ((uint32_t)h) << 16;
    return __builtin_bit_cast(float, u);
}
static __device__ __forceinline__ int r64(int x) {          // round to mult of 64
    return ((x + 32) >> 6) << 6;
}

#define GLOAD16(gp, lp) __builtin_amdgcn_global_load_lds(                      \
    (const __attribute__((address_space(1))) void*)(gp),                       \
    (__attribute__((address_space(3))) void*)(lp), 16, 0, 0)

// ---------------------------------------------------------------------------
// GEMM: C[M,N] = A[M,K] @ Bt[N,K]^T   (A, Bt bf16 row-major; Bt is B^T)
// BM=128, BK=64, BN=128. 256 threads = 4 waves (2x2 wave grid).
// m97-style SINGLE-buffered 2-barrier K-loop: stage -> __syncthreads (its
// implicit vmcnt/lgkmcnt drain publishes the tile) -> MFMA -> __syncthreads.
// Exposed staging latency is hidden by CO-RESIDENCY: 32 KB LDS -> 5
// blocks/CU (m114 wave-level overlap), vs 2 blocks/CU for the double-
// buffered variant whose explicit pipeline measured exactly neutral
// (r10->r11). XOR slot-swizzle on global source + ds_read address
// (0 bank conflicts). Bijective chunked XCD swizzle, y-fastest flatten.
// OM: 0=bf16 C[M,N]; 1=bf16 C[N,M]; 2=fp32 C[M,N]; 3=fp32 partial (split-K).
// SPLITK: even per-row split — k range [r64(z*Keff/NS), r64((z+1)*Keff/NS)).
// ---------------------------------------------------------------------------
template<int OM, bool CAUSAL, bool KCAP, bool SILU, bool SPLITK>
__global__ __launch_bounds__(256, 4)
void gemm_bt(const unsigned short* __restrict__ A,
             const unsigned short* __restrict__ Bt,
             void* __restrict__ Cp,
             int M, int N, int K, float scale, int rowBase, int NS)
{
    constexpr int BM = 128, BK = 64, BN = 128;
    constexpr int NF = BN / 32;           // 4 b-frags per wave
    __shared__ __align__(16) unsigned short As[BM * BK];   // 16 KB
    __shared__ __align__(16) unsigned short Bs[BN * BK];   // 16 KB

    const int t = threadIdx.x;
    const int lane = t & 63, w = t >> 6;
    const int wr = w >> 1, wc = w & 1;
    const int ln15 = lane & 15, hi = lane >> 4;

    // ---- chunked-bijective XCD swizzle, y-fastest flatten
    const int gx = gridDim.x, gy = gridDim.y;
    const int nwg = gx * gy * gridDim.z;
    const int orig = blockIdx.y + gy * (blockIdx.x + gx * blockIdx.z);
    const int q = nwg >> 3, r8 = nwg & 7;
    const int xcd = orig & 7, idx = orig >> 3;
    const int wg = (xcd < r8 ? xcd * (q + 1)
                             : r8 * (q + 1) + (xcd - r8) * q) + idx;
    const int byi = wg % gy, tmpw = wg / gy;
    const int bxi = tmpw % gx, bzi = tmpw / gx;

    const int bm = byi * BM, bn = bxi * BN;

    if (CAUSAL && bn > rowBase + bm + (BM - 1)) return;   // fully-masked tile
    int Keff = K;
    if (KCAP) { int kc = rowBase + bm + BM; Keff = kc < K ? kc : K; }
    int kbeg = 0, kend = Keff;
    if (SPLITK) {
        kbeg = r64(bzi * Keff / NS);
        int ke = r64((bzi + 1) * Keff / NS);
        kend = ke < Keff ? ke : Keff;
        if (kbeg >= kend) return;          // empty slice (small Keff rows)
    }

    f32x4 acc[4][NF] = {};

    for (int k0 = kbeg; k0 < kend; k0 += BK) {
        // ---- stage both tiles (8 x global_load_lds_dwordx4 per thread)
        #pragma unroll
        for (int i = 0; i < 4; ++i) {
            int c = t + 256 * i;
            int r = c >> 3, qq = (c & 7) ^ (r & 7);       // pre-swizzled src
            GLOAD16(A + (size_t)(bm + r) * K + k0 + qq * 8, As + c * 8);
        }
        #pragma unroll
        for (int i = 0; i < 4; ++i) {
            int c = t + 256 * i;
            int r = c >> 3, qq = (c & 7) ^ (r & 7);
            GLOAD16(Bt + (size_t)(bn + r) * K + k0 + qq * 8, Bs + c * 8);
        }
        __syncthreads();                   // drains loads, publishes tile

        #pragma unroll
        for (int kk = 0; kk < 2; ++kk) {
            short8 a[4], b[NF];
            #pragma unroll
            for (int m = 0; m < 4; ++m) {
                int r = wr * 64 + m * 16 + ln15;
                int s = (kk * 4 + hi) ^ (r & 7);          // swizzled read
                a[m] = *(const short8*)(As + r * 64 + s * 8);
            }
            #pragma unroll
            for (int n = 0; n < NF; ++n) {
                int r = wc * 64 + n * 16 + ln15;
                int s = (kk * 4 + hi) ^ (r & 7);
                b[n] = *(const short8*)(Bs + r * 64 + s * 8);
            }
            __builtin_amdgcn_s_setprio(1);
            #pragma unroll
            for (int m = 0; m < 4; ++m)
                #pragma unroll
                for (int n = 0; n < NF; ++n)
                    acc[m][n] = MFMA_BF16(a[m], b[n], acc[m][n], 0, 0, 0);
            __builtin_amdgcn_s_setprio(0);
        }
        __syncthreads();                   // all waves done reading the tile
    }

    // ---- epilogue: C/D layout col = lane&15, row = (lane>>4)*4 + j
    float* Pz = (OM == 3)
        ? (float*)Cp + (size_t)bzi * M * N : nullptr;
    #pragma unroll
    for (int m = 0; m < 4; ++m)
        #pragma unroll
        for (int n = 0; n < NF; ++n)
            #pragma unroll
            for (int j = 0; j < 4; ++j) {
                int row = bm + wr * 64 + m * 16 + hi * 4 + j;
                int col = bn + wc * 64 + n * 16 + ln15;
                float v = acc[m][n][j] * scale;
                if (SILU) v = v / (1.0f + __expf(-v));
                if (OM == 0)
                    ((unsigned short*)Cp)[(size_t)row * N + col] = f2bf(v);
                else if (OM == 1)
                    ((unsigned short*)Cp)[(size_t)col * M + row] = f2bf(v);
                else if (OM == 2)
                    ((float*)Cp)[(size_t)row * N + col] = v;
                else
                    Pz[(size_t)row * N + col] = v;
            }
}

// ---------------------------------------------------------------------------
// Split-K reduction: sum non-empty fp32 partial slices (same even per-row
// boundaries as the PV kernel), SiLU, bf16 -> out (band rows).
// ---------------------------------------------------------------------------
__global__ __launch_bounds__(256)
void reduce_silu(const float* __restrict__ part, unsigned short* __restrict__ out,
                 int ns, int rowBase)
{
    const size_t idx = ((size_t)blockIdx.x * 256 + threadIdx.x) * 8;
    const int r = (int)(idx >> 10);                 // DIM = 1024
    int keb = rowBase + ((r >> 7) << 7) + 128;      // Keff of r's PV block-row
    if (keb > SEQ) keb = SEQ;

    f32x4 s0 = {}, s1 = {};
    for (int z = 0; z < ns; ++z) {
        int b0 = r64(z * keb / ns);
        int b1 = r64((z + 1) * keb / ns);
        if (b1 > keb) b1 = keb;
        if (b1 > b0) {
            const float* p = part + (size_t)z * (2048 * 1024) + idx;
            s0 += *(const f32x4*)p;
            s1 += *(const f32x4*)(p + 4);
        }
    }
    short8 o;
    #pragma unroll
    for (int j = 0; j < 4; ++j) {
        float v = s0[j];
        o[j] = (short)f2bf(v / (1.0f + __expf(-v)));
    }
    #pragma unroll
    for (int j = 0; j < 4; ++j) {
        float v = s1[j];
        o[4 + j] = (short)f2bf(v / (1.0f + __expf(-v)));
    }
    *(short8*)(out + idx) = o;
}

// ---------------------------------------------------------------------------
// Row softmax over a 2048-row band of S (bf16 [2048][8192]), in place.
// Valid cols [0, grow], zero-fill to the 128 boundary Kcap.
// ---------------------------------------------------------------------------
__global__ __launch_bounds__(256)
void softmax_rows(unsigned short* __restrict__ S, int rowBase)
{
    __shared__ float red[4];
    const int r = blockIdx.x;
    const int grow = rowBase + r;
    const int Kcap = ((grow >> 7) + 1) << 7;
    unsigned short* row = S + (size_t)r * SEQ;
    const int t = threadIdx.x, lane = t & 63, w = t >> 6;

    float v[4][8];
    float mx = -1e30f;
    #pragma unroll
    for (int i = 0; i < 4; ++i) {
        int c0 = (i * 256 + t) * 8;
        if (c0 < Kcap) {
            short8 s8 = *(const short8*)(row + c0);
            #pragma unroll
            for (int j = 0; j < 8; ++j) {
                float f = bf2f((unsigned short)s8[j]);
                v[i][j] = (c0 + j <= grow) ? f : -1e30f;
                mx = fmaxf(mx, v[i][j]);
            }
        } else {
            #pragma unroll
            for (int j = 0; j < 8; ++j) v[i][j] = -1e30f;
        }
    }
    #pragma unroll
    for (int off = 32; off >= 1; off >>= 1)
        mx = fmaxf(mx, __shfl_xor(mx, off, 64));
    if (lane == 0) red[w] = mx;
    __syncthreads();
    mx = fmaxf(fmaxf(red[0], red[1]), fmaxf(red[2], red[3]));
    __syncthreads();

    float sum = 0.f;
    #pragma unroll
    for (int i = 0; i < 4; ++i)
        #pragma unroll
        for (int j = 0; j < 8; ++j) {
            float p = (v[i][j] > -1e29f) ? __expf(v[i][j] - mx) : 0.f;
            v[i][j] = p;
            sum += p;
        }
    #pragma unroll
    for (int off = 32; off >= 1; off >>= 1)
        sum += __shfl_xor(sum, off, 64);
    if (lane == 0) red[w] = sum;
    __syncthreads();
    sum = red[0] + red[1] + red[2] + red[3];
    const float inv = 1.0f / sum;

    #pragma unroll
    for (int i = 0; i < 4; ++i) {
        int c0 = (i * 256 + t) * 8;
        if (c0 < Kcap) {
            short8 o;
            #pragma unroll
            for (int j = 0; j < 8; ++j) o[j] = (short)f2bf(v[i][j] * inv);
            *(short8*)(row + c0) = o;
        }
    }
}

// ---------------------------------------------------------------------------
__global__ __launch_bounds__(256)
void cvt_bf16(const float* __restrict__ X, unsigned short* __restrict__ Y)
{
    int i = (blockIdx.x * 256 + threadIdx.x) * 8;
    f32x4 v0 = *(const f32x4*)(X + i);
    f32x4 v1 = *(const f32x4*)(X + i + 4);
    short8 o = { (short)f2bf(v0[0]), (short)f2bf(v0[1]),
                 (short)f2bf(v0[2]), (short)f2bf(v0[3]),
                 (short)f2bf(v1[0]), (short)f2bf(v1[1]),
                 (short)f2bf(v1[2]), (short)f2bf(v1[3]) };
    *(short8*)(Y + i) = o;
}

// ---------------------------------------------------------------------------
__global__ __launch_bounds__(256)
void twT(const float* __restrict__ W, unsigned short* __restrict__ WT)
{
    __shared__ float tile[64][65];
    const int bx = blockIdx.x * 64, by = blockIdx.y * 64;
    const int t = threadIdx.x, rr = t >> 4, c4 = (t & 15) * 4;
    #pragma unroll
    for (int i = 0; i < 4; ++i) {
        int r = rr + i * 16;
        f32x4 v = *(const f32x4*)(W + (size_t)(by + r) * DIM + bx + c4);
        tile[r][c4 + 0] = v[0]; tile[r][c4 + 1] = v[1];
        tile[r][c4 + 2] = v[2]; tile[r][c4 + 3] = v[3];
    }
    __syncthreads();
    #pragma unroll
    for (int i = 0; i < 4; ++i) {
        int r = rr + i * 16;                           // WT row = bx + r
        us4 o = { f2bf(tile[c4 + 0][r]), f2bf(tile[c4 + 1][r]),
                  f2bf(tile[c4 + 2][r]), f2bf(tile[c4 + 3][r]) };
        *(us4*)(WT + (size_t)(bx + r) * DIM + by + c4) = o;
    }
}

// ---------------------------------------------------------------------------
extern "C" void kernel_launch(void* const* d_in, const int* in_sizes, int n_in,
                              void* d_out, int out_size, void* d_ws, size_t ws_size,
                              hipStream_t stream)
{
    const float* x   = (const float*)d_in[0];
    const float* wq  = (const float*)d_in[1];
    const float* wk  = (const float*)d_in[2];
    const float* wv1 = (const float*)d_in[3];
    const float* wv2 = (const float*)d_in[4];

    // ws: Q/H bf16 [S,D] | K bf16 [S,D] | V^T bf16 [D,S] | split-K partials
    const size_t BUF = (size_t)SEQ * DIM * sizeof(unsigned short);  // 16 MiB
    unsigned short* qbuf  = (unsigned short*)d_ws;
    unsigned short* kbuf  = qbuf + (size_t)SEQ * DIM;
    unsigned short* vtbuf = kbuf + (size_t)SEQ * DIM;
    float* part = (float*)((char*)d_ws + 3 * BUF);
    const size_t PSZ = (size_t)2048 * 1024 * sizeof(float);         // 8 MiB
    int nsplit = 0;
    if (ws_size >= 3 * BUF + 2 * PSZ) {
        size_t ns = (ws_size - 3 * BUF) / PSZ;
        nsplit = (int)(ns < 4 ? ns : 4);
    }

    // d_out staging: xb + wT's during projections, then S bands.
    unsigned short* xb    = (unsigned short*)d_out;
    unsigned short* wqT   = xb + (size_t)SEQ * DIM;
    unsigned short* wkT   = wqT + DIM * DIM;
    unsigned short* wv1T  = wkT + DIM * DIM;
    unsigned short* Sband = (unsigned short*)d_out;

    dim3 tg(16, 16);
    cvt_bf16<<<SEQ * DIM / 2048, 256, 0, stream>>>(x, xb);
    twT<<<tg, 256, 0, stream>>>(wq,  wqT);
    twT<<<tg, 256, 0, stream>>>(wk,  wkT);
    twT<<<tg, 256, 0, stream>>>(wv1, wv1T);

    dim3 gproj(DIM / 128, SEQ / 128);
    gemm_bt<0,false,false,false,false><<<gproj, 256, 0, stream>>>(
        xb, wqT,  qbuf,  SEQ, DIM, DIM, 1.0f, 0, 0);
    gemm_bt<0,false,false,false,false><<<gproj, 256, 0, stream>>>(
        xb, wkT,  kbuf,  SEQ, DIM, DIM, 1.0f, 0, 0);
    gemm_bt<1,false,false,false,false><<<gproj, 256, 0, stream>>>(
        xb, wv1T, vtbuf, SEQ, DIM, DIM, 1.0f, 0, 0);

    constexpr int BAND = 2048;
    for (int b = 0; b < 4; ++b) {
        const int rb = b * BAND;
        const int ncol = (rb + BAND) / 128;        // prune all-masked columns
        dim3 gq(ncol, BAND / 128);
        gemm_bt<0,true,false,false,false><<<gq, 256, 0, stream>>>(
            qbuf + (size_t)rb * DIM, kbuf, Sband, BAND, SEQ, DIM, 0.03125f, rb, 0);
        if (b == 3)  // K no longer needed: stage wv2^T into kbuf
            twT<<<tg, 256, 0, stream>>>(wv2, kbuf);
        softmax_rows<<<BAND, 256, 0, stream>>>(Sband, rb);
        if (nsplit >= 2) {
            dim3 gpv(DIM / 128, BAND / 128, nsplit);
            gemm_bt<3,false,true,false,true><<<gpv, 256, 0, stream>>>(
                Sband, vtbuf, part, BAND, DIM, SEQ, 1.0f, rb, nsplit);
            reduce_silu<<<BAND * DIM / 2048, 256, 0, stream>>>(
                part, qbuf + (size_t)rb * DIM, nsplit, rb);
        } else {
            dim3 gpv(DIM / 128, BAND / 128);
            gemm_bt<0,false,true,true,false><<<gpv, 256, 0, stream>>>(
                Sband, vtbuf, qbuf + (size_t)rb * DIM, BAND, DIM, SEQ, 1.0f, rb, 0);
        }
    }

    gemm_bt<2,false,false,false,false><<<gproj, 256, 0, stream>>>(
        qbuf, kbuf, d_out, SEQ, DIM, DIM, 1.0f, 0, 0);
}